// Round 1
// baseline (780.446 us; speedup 1.0000x reference)
//
#include <hip/hip_runtime.h>
#include <hip/hip_bf16.h>
#include <cstdint>

#define D_DIM 128
#define N0_C 50000
#define N1_C 5000
#define E0_C 800000
#define E1_C 80000

// ---------------------------------------------------------------------------
// CSR build: histogram -> exclusive scan -> fill
// ---------------------------------------------------------------------------
__global__ __launch_bounds__(256) void hist_kernel(const int* __restrict__ dst,
                                                   int* __restrict__ cnt, int E) {
    int e = blockIdx.x * blockDim.x + threadIdx.x;
    if (e < E) atomicAdd(&cnt[dst[e]], 1);
}

// single-block exclusive scan: rowptr[0]=0, rowptr[i+1]=sum(cnt[0..i])
__global__ __launch_bounds__(1024) void exscan_kernel(const int* __restrict__ cnt,
                                                      int* __restrict__ rowptr, int n) {
    __shared__ int wsum[17];
    __shared__ int base_s;
    const int t = threadIdx.x;
    const int lane = t & 63;
    const int w = t >> 6;
    if (t == 0) { base_s = 0; rowptr[0] = 0; }
    __syncthreads();
    for (int i0 = 0; i0 < n; i0 += 1024) {
        int i = i0 + t;
        int v = (i < n) ? cnt[i] : 0;
        // wave inclusive scan
        int x = v;
        #pragma unroll
        for (int off = 1; off < 64; off <<= 1) {
            int y = __shfl_up(x, off);
            if (lane >= off) x += y;
        }
        if (lane == 63) wsum[w] = x;
        __syncthreads();
        if (t == 0) {
            int run = base_s;
            #pragma unroll
            for (int j = 0; j < 16; ++j) { int c = wsum[j]; wsum[j] = run; run += c; }
            wsum[16] = run;
        }
        __syncthreads();
        if (i < n) rowptr[i + 1] = wsum[w] + x;
        __syncthreads();
        if (t == 0) base_s = wsum[16];
        __syncthreads();
    }
}

__global__ __launch_bounds__(256) void fill_kernel(const int* __restrict__ src,
                                                   const int* __restrict__ dst,
                                                   const int* __restrict__ rowptr,
                                                   int* __restrict__ cursor,
                                                   int* __restrict__ colv, int E) {
    int e = blockIdx.x * blockDim.x + threadIdx.x;
    if (e < E) {
        int d = dst[e];
        int p = atomicAdd(&cursor[d], 1);
        colv[rowptr[d] + p] = src[e];
    }
}

// ---------------------------------------------------------------------------
// Dual GEMM: O1 = X@W1 (+bias1), O2 = X@W2.  X:[N,128], W:[128,128] row-major.
// Block: 256 threads, 32 rows/block. Thread computes 4 rows x 4 cols x 2 mats.
// ---------------------------------------------------------------------------
__global__ __launch_bounds__(256) void dualmm_kernel(
    const float* __restrict__ Xin, const float* __restrict__ W1,
    const float* __restrict__ W2, const float* __restrict__ bias1,
    float* __restrict__ O1, float* __restrict__ O2, int N) {
    __shared__ float As[32 * D_DIM];
    const int tid = threadIdx.x;
    const int m0 = blockIdx.x * 32;
    {
        const float4* __restrict__ Xv = (const float4*)Xin;
        float4* Asv = (float4*)As;
        #pragma unroll
        for (int i = 0; i < 4; ++i) {
            int idx = tid + i * 256;      // 0..1023 float4 slots
            int r = idx >> 5, c = idx & 31;
            int gr = m0 + r;
            float4 v = make_float4(0.f, 0.f, 0.f, 0.f);
            if (gr < N) v = Xv[(size_t)gr * 32 + c];
            Asv[idx] = v;
        }
    }
    __syncthreads();
    const int tx = tid & 31, ty = tid >> 5;
    const int col = tx << 2;   // output col base
    const int row = ty << 2;   // tile row base
    float acc1[4][4], acc2[4][4];
    #pragma unroll
    for (int r = 0; r < 4; ++r)
        #pragma unroll
        for (int c = 0; c < 4; ++c) { acc1[r][c] = 0.f; acc2[r][c] = 0.f; }

    for (int k0 = 0; k0 < D_DIM; k0 += 4) {
        float4 a[4];
        #pragma unroll
        for (int r = 0; r < 4; ++r)
            a[r] = *(const float4*)&As[(row + r) * D_DIM + k0];
        float4 w1[4], w2[4];
        #pragma unroll
        for (int kk = 0; kk < 4; ++kk) {
            w1[kk] = *(const float4*)&W1[(size_t)(k0 + kk) * D_DIM + col];
            w2[kk] = *(const float4*)&W2[(size_t)(k0 + kk) * D_DIM + col];
        }
        #pragma unroll
        for (int kk = 0; kk < 4; ++kk) {
            #pragma unroll
            for (int r = 0; r < 4; ++r) {
                float av = (kk == 0) ? a[r].x : (kk == 1) ? a[r].y
                         : (kk == 2) ? a[r].z : a[r].w;
                acc1[r][0] += av * w1[kk].x; acc1[r][1] += av * w1[kk].y;
                acc1[r][2] += av * w1[kk].z; acc1[r][3] += av * w1[kk].w;
                acc2[r][0] += av * w2[kk].x; acc2[r][1] += av * w2[kk].y;
                acc2[r][2] += av * w2[kk].z; acc2[r][3] += av * w2[kk].w;
            }
        }
    }
    float4 bv = make_float4(0.f, 0.f, 0.f, 0.f);
    if (bias1) bv = *(const float4*)&bias1[col];
    #pragma unroll
    for (int r = 0; r < 4; ++r) {
        int gr = m0 + row + r;
        if (gr < N) {
            float4 o1 = make_float4(acc1[r][0] + bv.x, acc1[r][1] + bv.y,
                                    acc1[r][2] + bv.z, acc1[r][3] + bv.w);
            float4 o2 = make_float4(acc2[r][0], acc2[r][1], acc2[r][2], acc2[r][3]);
            *(float4*)&O1[(size_t)gr * D_DIM + col] = o1;
            *(float4*)&O2[(size_t)gr * D_DIM + col] = o2;
        }
    }
}

// ---------------------------------------------------------------------------
// CSR gather-aggregate (atomic-free): one wave per dst node, float2 per lane.
// out[n] = maybe_relu( (sum_{j} feat[col[j]]) / max(deg,1) + add[n]? + bias? )
// ---------------------------------------------------------------------------
__global__ __launch_bounds__(256) void csr_agg_kernel(
    const float* __restrict__ feat, const int* __restrict__ rowptr,
    const int* __restrict__ colv, const float* __restrict__ addv,
    const float* __restrict__ bias, float* __restrict__ out,
    int Ndst, int do_relu) {
    int gt = blockIdx.x * blockDim.x + threadIdx.x;
    int wid = gt >> 6;
    int lane = threadIdx.x & 63;
    if (wid >= Ndst) return;
    int beg = rowptr[wid], end = rowptr[wid + 1];
    float ax = 0.f, ay = 0.f;
    const int f = lane << 1;
    int j = beg;
    for (; j + 1 < end; j += 2) {
        int s0 = colv[j], s1 = colv[j + 1];
        float2 v0 = *(const float2*)&feat[(size_t)s0 * D_DIM + f];
        float2 v1 = *(const float2*)&feat[(size_t)s1 * D_DIM + f];
        ax += v0.x; ay += v0.y;
        ax += v1.x; ay += v1.y;
    }
    if (j < end) {
        int s0 = colv[j];
        float2 v0 = *(const float2*)&feat[(size_t)s0 * D_DIM + f];
        ax += v0.x; ay += v0.y;
    }
    float inv = 1.f / fmaxf((float)(end - beg), 1.f);
    ax *= inv; ay *= inv;
    if (addv) { float2 v = *(const float2*)&addv[(size_t)wid * D_DIM + f]; ax += v.x; ay += v.y; }
    if (bias) { float2 v = *(const float2*)&bias[f]; ax += v.x; ay += v.y; }
    if (do_relu) { ax = fmaxf(ax, 0.f); ay = fmaxf(ay, 0.f); }
    *(float2*)&out[(size_t)wid * D_DIM + f] = make_float2(ax, ay);
}

// ---------------------------------------------------------------------------
// Up-sweep scatter: per up-edge e: y2s[ds[e]] += C[dd[e]] + A[ds[e]]
//                                  y2n[ds[e]] += Dm[dd[e]] + B[ds[e]]
// One wave per edge, float2 per lane, HW float atomics.
// ---------------------------------------------------------------------------
__global__ __launch_bounds__(256) void upscatter_kernel(
    const float* __restrict__ Cb, const float* __restrict__ Db,   // [N1,128]
    const float* __restrict__ Ab, const float* __restrict__ Bb,   // [N0,128]
    const int* __restrict__ dsrc, const int* __restrict__ ddst,
    float* __restrict__ y2s, float* __restrict__ y2n, int E) {
    int gt = blockIdx.x * blockDim.x + threadIdx.x;
    int wid = gt >> 6;
    int lane = threadIdx.x & 63;
    if (wid >= E) return;
    int n = dsrc[wid], c = ddst[wid];
    const int f = lane << 1;
    float2 cv = *(const float2*)&Cb[(size_t)c * D_DIM + f];
    float2 av = *(const float2*)&Ab[(size_t)n * D_DIM + f];
    float2 dv = *(const float2*)&Db[(size_t)c * D_DIM + f];
    float2 bv = *(const float2*)&Bb[(size_t)n * D_DIM + f];
    unsafeAtomicAdd(&y2s[(size_t)n * D_DIM + f],     cv.x + av.x);
    unsafeAtomicAdd(&y2s[(size_t)n * D_DIM + f + 1], cv.y + av.y);
    unsafeAtomicAdd(&y2n[(size_t)n * D_DIM + f],     dv.x + bv.x);
    unsafeAtomicAdd(&y2n[(size_t)n * D_DIM + f + 1], dv.y + bv.y);
}

// ---------------------------------------------------------------------------
// Readout: z[n] = dot(x0f[n], Wm) + bm   (one wave per node)
// ---------------------------------------------------------------------------
__global__ __launch_bounds__(256) void readout_kernel(
    const float* __restrict__ x0f, const float* __restrict__ Wm,
    const float* __restrict__ bm, float* __restrict__ z, int N) {
    int gt = blockIdx.x * blockDim.x + threadIdx.x;
    int wid = gt >> 6;
    int lane = threadIdx.x & 63;
    if (wid >= N) return;
    const int f = lane << 1;
    float2 v = *(const float2*)&x0f[(size_t)wid * D_DIM + f];
    float2 w = *(const float2*)&Wm[f];
    float p = v.x * w.x + v.y * w.y;
    #pragma unroll
    for (int off = 32; off > 0; off >>= 1) p += __shfl_down(p, off);
    if (lane == 0) z[wid] = p + bm[0];
}

__global__ __launch_bounds__(1024) void softmax_reduce_kernel(
    const float* __restrict__ z, float* __restrict__ red, int N) {
    __shared__ float s[1024];
    int t = threadIdx.x;
    float m = -1e30f;
    for (int i = t; i < N; i += 1024) m = fmaxf(m, z[i]);
    s[t] = m; __syncthreads();
    for (int off = 512; off > 0; off >>= 1) {
        if (t < off) s[t] = fmaxf(s[t], s[t + off]);
        __syncthreads();
    }
    float mx = s[0]; __syncthreads();
    float sum = 0.f;
    for (int i = t; i < N; i += 1024) sum += expf(z[i] - mx);
    s[t] = sum; __syncthreads();
    for (int off = 512; off > 0; off >>= 1) {
        if (t < off) s[t] += s[t + off];
        __syncthreads();
    }
    if (t == 0) { red[0] = mx; red[1] = s[0]; }
}

__global__ __launch_bounds__(256) void softmax_final_kernel(
    const float* __restrict__ z, const float* __restrict__ red,
    float* __restrict__ out, int N) {
    int i = blockIdx.x * blockDim.x + threadIdx.x;
    if (i < N) out[i] = expf(z[i] - red[0]) / red[1];
}

// ---------------------------------------------------------------------------
// Host launcher
// ---------------------------------------------------------------------------
static inline char* align_up(char* p, size_t a) {
    return (char*)(((uintptr_t)p + a - 1) & ~(uintptr_t)(a - 1));
}

extern "C" void kernel_launch(void* const* d_in, const int* in_sizes, int n_in,
                              void* d_out, int out_size, void* d_ws, size_t ws_size,
                              hipStream_t stream) {
    const int N0 = N0_C, N1 = N1_C, E0 = E0_C, E1 = E1_C;
    const float* X   = (const float*)d_in[0];
    const float* W0s = (const float*)d_in[1];
    const float* W0n = (const float*)d_in[2];
    const float* b0  = (const float*)d_in[3];
    const float* W1s = (const float*)d_in[4];
    const float* W1n = (const float*)d_in[5];
    const float* b1  = (const float*)d_in[6];
    const float* W2s = (const float*)d_in[7];   // [256,128]: rows 0..127 -> x1 part, 128..255 -> x0 part
    const float* W2n = (const float*)d_in[8];
    const float* b2  = (const float*)d_in[9];
    const float* Wm  = (const float*)d_in[10];
    const float* bm  = (const float*)d_in[11];
    const int* src0  = (const int*)d_in[12];
    const int* dst0  = (const int*)d_in[13];
    const int* src1  = (const int*)d_in[14];
    const int* dst1  = (const int*)d_in[15];
    const int* dsrc  = (const int*)d_in[16];    // down_src (lv0 node per down-edge)
    const int* ddst  = (const int*)d_in[17];    // down_dst (lv1 cluster per down-edge)
    float* out = (float*)d_out;

    // ---- workspace carve-up (bump allocator, 256B aligned) ----
    char* p = (char*)d_ws;
    const size_t FB = (size_t)N0 * D_DIM;       // floats per big node buffer
    const size_t SB = (size_t)N1 * D_DIM;
    auto grab_f = [&](size_t nfloats) { p = align_up(p, 256); float* r = (float*)p; p += nfloats * 4; return r; };
    auto grab_i = [&](size_t nints)   { p = align_up(p, 256); int*   r = (int*)p;   p += nints * 4;   return r; };

    float* bufA = grab_f(FB);   // y0s(+b0) -> x0
    float* bufB = grab_f(FB);   // y0n -> A2 (x0@W2s_bot)
    float* bufC = grab_f(FB);   // B2 (x0@W2n_bot)
    float* bufD = grab_f(FB);   // y2s -> x0f     (bufD,bufE must stay adjacent for one memset)
    float* bufE = grab_f(FB);   // y2nn
    float* x1b  = grab_f(SB);
    float* y1s  = grab_f(SB);   // -> x1f
    float* y1n  = grab_f(SB);
    float* C2   = grab_f(SB);   // x1f@W2s_top
    float* D2   = grab_f(SB);   // x1f@W2n_top
    float* zbuf = grab_f(N0);
    float* red  = grab_f(8);
    int* cnt0 = grab_i(N0);     // cnt0,cnt1,cntD contiguous -> single memset
    int* cnt1 = (int*)(((char*)cnt0) + (size_t)N0 * 4);
    int* cntD = (int*)(((char*)cnt1) + (size_t)N1 * 4);
    p = (char*)(cntD + N1);
    int* rowptr0 = grab_i(N0 + 1);
    int* rowptr1 = grab_i(N1 + 1);
    int* rowptrD = grab_i(N1 + 1);
    int* col0 = grab_i(E0);
    int* col1 = grab_i(E1);
    int* colD = grab_i(N0);
    (void)ws_size; (void)n_in; (void)in_sizes; (void)out_size;

    const int BT = 256;
    auto cdiv = [](int a, int b) { return (a + b - 1) / b; };

    // ---- CSR build for graph0, graph1, down-edges ----
    hipMemsetAsync(cnt0, 0, (size_t)(N0 + 2 * N1) * 4, stream);
    hist_kernel<<<cdiv(E0, BT), BT, 0, stream>>>(dst0, cnt0, E0);
    hist_kernel<<<cdiv(E1, BT), BT, 0, stream>>>(dst1, cnt1, E1);
    hist_kernel<<<cdiv(N0, BT), BT, 0, stream>>>(ddst, cntD, N0);
    exscan_kernel<<<1, 1024, 0, stream>>>(cnt0, rowptr0, N0);
    exscan_kernel<<<1, 1024, 0, stream>>>(cnt1, rowptr1, N1);
    exscan_kernel<<<1, 1024, 0, stream>>>(cntD, rowptrD, N1);
    hipMemsetAsync(cnt0, 0, (size_t)(N0 + 2 * N1) * 4, stream);
    fill_kernel<<<cdiv(E0, BT), BT, 0, stream>>>(src0, dst0, rowptr0, cnt0, col0, E0);
    fill_kernel<<<cdiv(E1, BT), BT, 0, stream>>>(src1, dst1, rowptr1, cnt1, col1, E1);
    fill_kernel<<<cdiv(N0, BT), BT, 0, stream>>>(dsrc, ddst, rowptrD, cntD, colD, N0);

    // ---- layer 0 SAGE: x0 = X@W0s + b0 + mean_nbr(X@W0n) ----
    dualmm_kernel<<<cdiv(N0, 32), BT, 0, stream>>>(X, W0s, W0n, b0, bufA, bufB, N0);
    csr_agg_kernel<<<cdiv(N0, 4), BT, 0, stream>>>(bufB, rowptr0, col0, bufA, nullptr, bufA, N0, 0);

    // ---- down pool: x1 = relu(mean_cluster(x0)) ----
    csr_agg_kernel<<<cdiv(N1, 4), BT, 0, stream>>>(bufA, rowptrD, colD, nullptr, nullptr, x1b, N1, 1);

    // ---- layer 1 SAGE: x1f = relu(x1@W1s + b1 + mean_nbr(x1@W1n)) ----
    dualmm_kernel<<<cdiv(N1, 32), BT, 0, stream>>>(x1b, W1s, W1n, b1, y1s, y1n, N1);
    csr_agg_kernel<<<cdiv(N1, 4), BT, 0, stream>>>(y1n, rowptr1, col1, y1s, nullptr, y1s, N1, 1);

    // ---- layer 2 per-node matmuls (linearity: matmul before scatter/aggregate) ----
    dualmm_kernel<<<cdiv(N0, 32), BT, 0, stream>>>(bufA, W2s + 128 * D_DIM, W2n + 128 * D_DIM,
                                                   nullptr, bufB, bufC, N0);
    dualmm_kernel<<<cdiv(N1, 32), BT, 0, stream>>>(y1s, W2s, W2n, nullptr, C2, D2, N1);

    // ---- up-sweep scatter into y2s/y2nn ----
    hipMemsetAsync(bufD, 0, 2 * FB * 4, stream);
    upscatter_kernel<<<cdiv(N0, 4), BT, 0, stream>>>(C2, D2, bufB, bufC, dsrc, ddst, bufD, bufE, N0);

    // ---- layer 2 SAGE combine: x0f = relu(y2s + b2 + mean_nbr(y2nn)) ----
    csr_agg_kernel<<<cdiv(N0, 4), BT, 0, stream>>>(bufE, rowptr0, col0, bufD, b2, bufD, N0, 1);

    // ---- readout + softmax over nodes ----
    readout_kernel<<<cdiv(N0, 4), BT, 0, stream>>>(bufD, Wm, bm, zbuf, N0);
    softmax_reduce_kernel<<<1, 1024, 0, stream>>>(zbuf, red, N0);
    softmax_final_kernel<<<cdiv(N0, BT), BT, 0, stream>>>(zbuf, red, out, N0);
}

// Round 2
// 578.857 us; speedup vs baseline: 1.3483x; 1.3483x over previous
//
#include <hip/hip_runtime.h>
#include <hip/hip_bf16.h>
#include <cstdint>

#define D_DIM 128
#define N0_C 50000
#define N1_C 5000
#define E0_C 800000
#define E1_C 80000

typedef __attribute__((ext_vector_type(8))) short bf16x8;
typedef __attribute__((ext_vector_type(4))) float f32x4;

__device__ __forceinline__ ushort f2bf_rne(float x) {
    unsigned int u = __float_as_uint(x);
    return (ushort)((u + 0x7FFFu + ((u >> 16) & 1u)) >> 16);
}
__device__ __forceinline__ float bf2f(ushort h) {
    return __uint_as_float(((unsigned int)h) << 16);
}

// ---------------------------------------------------------------------------
// CSR build: histogram -> exclusive scan -> fill
// ---------------------------------------------------------------------------
__global__ __launch_bounds__(256) void hist_kernel(const int* __restrict__ dst,
                                                   int* __restrict__ cnt, int E) {
    int e = blockIdx.x * blockDim.x + threadIdx.x;
    if (e < E) atomicAdd(&cnt[dst[e]], 1);
}

__global__ __launch_bounds__(1024) void exscan_kernel(const int* __restrict__ cnt,
                                                      int* __restrict__ rowptr, int n) {
    __shared__ int wsum[17];
    __shared__ int base_s;
    const int t = threadIdx.x;
    const int lane = t & 63;
    const int w = t >> 6;
    if (t == 0) { base_s = 0; rowptr[0] = 0; }
    __syncthreads();
    for (int i0 = 0; i0 < n; i0 += 1024) {
        int i = i0 + t;
        int v = (i < n) ? cnt[i] : 0;
        int x = v;
        #pragma unroll
        for (int off = 1; off < 64; off <<= 1) {
            int y = __shfl_up(x, off);
            if (lane >= off) x += y;
        }
        if (lane == 63) wsum[w] = x;
        __syncthreads();
        if (t == 0) {
            int run = base_s;
            #pragma unroll
            for (int j = 0; j < 16; ++j) { int c = wsum[j]; wsum[j] = run; run += c; }
            wsum[16] = run;
        }
        __syncthreads();
        if (i < n) rowptr[i + 1] = wsum[w] + x;
        __syncthreads();
        if (t == 0) base_s = wsum[16];
        __syncthreads();
    }
}

__global__ __launch_bounds__(256) void fill_kernel(const int* __restrict__ src,
                                                   const int* __restrict__ dst,
                                                   const int* __restrict__ rowptr,
                                                   int* __restrict__ cursor,
                                                   int* __restrict__ colv, int E) {
    int e = blockIdx.x * blockDim.x + threadIdx.x;
    if (e < E) {
        int d = dst[e];
        int p = atomicAdd(&cursor[d], 1);
        colv[rowptr[d] + p] = src[e];
    }
}

// ---------------------------------------------------------------------------
// Weight prep: 8 logical 128x128 matrices -> W^T hi/lo bf16 planes [n][k]
// mats: 0:W0s 1:W0n 2:W1s 3:W1n 4:W2s_top 5:W2s_bot 6:W2n_top 7:W2n_bot
// ---------------------------------------------------------------------------
__global__ __launch_bounds__(256) void wprep_kernel(
    const float* __restrict__ W0s, const float* __restrict__ W0n,
    const float* __restrict__ W1s, const float* __restrict__ W1n,
    const float* __restrict__ W2s, const float* __restrict__ W2n,
    ushort* __restrict__ wt_hi, ushort* __restrict__ wt_lo) {
    int gi = blockIdx.x * 256 + threadIdx.x;     // 0 .. 8*16384-1
    int mi = gi >> 14, idx = gi & 16383;
    int k = idx >> 7, n = idx & 127;
    const float* src; int row = k;
    switch (mi) {
        case 0: src = W0s; break;
        case 1: src = W0n; break;
        case 2: src = W1s; break;
        case 3: src = W1n; break;
        case 4: src = W2s; break;
        case 5: src = W2s; row = k + 128; break;
        case 6: src = W2n; break;
        default: src = W2n; row = k + 128; break;
    }
    float v = src[row * 128 + n];
    ushort h = f2bf_rne(v);
    ushort l = f2bf_rne(v - bf2f(h));
    wt_hi[(mi << 14) + n * 128 + k] = h;
    wt_lo[(mi << 14) + n * 128 + k] = l;
}

// fp32 [N,128] -> hi/lo bf16 planes
__global__ __launch_bounds__(256) void tobf16_kernel(const float* __restrict__ in,
    ushort* __restrict__ hi, ushort* __restrict__ lo, int n2) {
    int i = blockIdx.x * 256 + threadIdx.x;
    if (i >= n2) return;
    float2 v = ((const float2*)in)[i];
    ushort h0 = f2bf_rne(v.x), h1 = f2bf_rne(v.y);
    ushort l0 = f2bf_rne(v.x - bf2f(h0)), l1 = f2bf_rne(v.y - bf2f(h1));
    ((ushort2*)hi)[i] = make_ushort2(h0, h1);
    ((ushort2*)lo)[i] = make_ushort2(l0, l1);
}

// ---------------------------------------------------------------------------
// Split-bf16 MFMA dual GEMM: O1 = A@W1 (+bias), O2 = A@W2 (fp32-accurate).
// A given as hi/lo bf16 planes [N,128]; W as W^T hi/lo planes [128n][128k].
// Block 256 thr = 4 waves, 64 rows/block; wave = 16-row tile x 128 cols x 2 mats.
// W^T k-slabs staged in LDS (40KB -> 4 blocks/CU).
// ---------------------------------------------------------------------------
__global__ __launch_bounds__(256) void dualmm_mfma_kernel(
    const ushort* __restrict__ Ahi, const ushort* __restrict__ Alo,
    const ushort* __restrict__ w1hi, const ushort* __restrict__ w1lo,
    const ushort* __restrict__ w2hi, const ushort* __restrict__ w2lo,
    const float* __restrict__ bias1,
    float* __restrict__ O1, float* __restrict__ O2, int N) {
    __shared__ __align__(16) ushort wslab[4][128][40];   // [plane][n][32k + 8 pad]
    const int tid = threadIdx.x;
    const int wave = tid >> 6, lane = tid & 63;
    const int m = lane & 15, quad = lane >> 4;
    const int r0 = blockIdx.x * 64 + wave * 16;
    const f32x4 zero = {0.f, 0.f, 0.f, 0.f};
    f32x4 acc1[8], acc2[8];
    #pragma unroll
    for (int ct = 0; ct < 8; ++ct) { acc1[ct] = zero; acc2[ct] = zero; }

    const ushort* wp[4] = {w1hi, w1lo, w2hi, w2lo};
    int ar = r0 + m; if (ar >= N) ar = N - 1;   // clamp; OOB rows masked at store

    for (int c = 0; c < 4; ++c) {
        const int k0 = c * 32;
        if (c) __syncthreads();
        #pragma unroll
        for (int p = 0; p < 4; ++p) {
            const ushort* w = wp[p];
            #pragma unroll
            for (int i = 0; i < 2; ++i) {
                int idx = tid + i * 256;         // 0..511
                int row = idx >> 2, ko = (idx & 3) * 8;
                uint4 v = *(const uint4*)(w + row * 128 + k0 + ko);
                *(uint4*)&wslab[p][row][ko] = v;
            }
        }
        __syncthreads();
        bf16x8 afh = *(const bf16x8*)(Ahi + (size_t)ar * 128 + k0 + quad * 8);
        bf16x8 afl = *(const bf16x8*)(Alo + (size_t)ar * 128 + k0 + quad * 8);
        #pragma unroll
        for (int ct = 0; ct < 8; ++ct) {
            const int n = ct * 16 + m;
            bf16x8 b1h = *(const bf16x8*)&wslab[0][n][quad * 8];
            bf16x8 b1l = *(const bf16x8*)&wslab[1][n][quad * 8];
            bf16x8 b2h = *(const bf16x8*)&wslab[2][n][quad * 8];
            bf16x8 b2l = *(const bf16x8*)&wslab[3][n][quad * 8];
            acc1[ct] = __builtin_amdgcn_mfma_f32_16x16x32_bf16(afh, b1h, acc1[ct], 0, 0, 0);
            acc1[ct] = __builtin_amdgcn_mfma_f32_16x16x32_bf16(afl, b1h, acc1[ct], 0, 0, 0);
            acc1[ct] = __builtin_amdgcn_mfma_f32_16x16x32_bf16(afh, b1l, acc1[ct], 0, 0, 0);
            acc2[ct] = __builtin_amdgcn_mfma_f32_16x16x32_bf16(afh, b2h, acc2[ct], 0, 0, 0);
            acc2[ct] = __builtin_amdgcn_mfma_f32_16x16x32_bf16(afl, b2h, acc2[ct], 0, 0, 0);
            acc2[ct] = __builtin_amdgcn_mfma_f32_16x16x32_bf16(afh, b2l, acc2[ct], 0, 0, 0);
        }
    }
    // epilogue: C/D layout col=lane&15, row=quad*4+reg
    #pragma unroll
    for (int ct = 0; ct < 8; ++ct) {
        const int col = ct * 16 + m;
        float bv = bias1 ? bias1[col] : 0.f;
        #pragma unroll
        for (int reg = 0; reg < 4; ++reg) {
            int r = r0 + quad * 4 + reg;
            if (r < N) {
                O1[(size_t)r * D_DIM + col] = acc1[ct][reg] + bv;
                O2[(size_t)r * D_DIM + col] = acc2[ct][reg];
            }
        }
    }
}

// ---------------------------------------------------------------------------
// CSR gather-aggregate (atomic-free): one wave per dst node, float2 per lane.
// out = maybe_relu( sum feat[col[j]] / max(deg,1) + add? + bias? ); optional
// bf16 hi/lo plane outputs for downstream MFMA consumption.
// ---------------------------------------------------------------------------
__global__ __launch_bounds__(256) void csr_agg_kernel(
    const float* __restrict__ feat, const int* __restrict__ rowptr,
    const int* __restrict__ colv, const float* __restrict__ addv,
    const float* __restrict__ bias, float* __restrict__ out,
    ushort* __restrict__ ohi, ushort* __restrict__ olo,
    int Ndst, int do_relu) {
    int gt = blockIdx.x * blockDim.x + threadIdx.x;
    int wid = gt >> 6;
    int lane = threadIdx.x & 63;
    if (wid >= Ndst) return;
    int beg = rowptr[wid], end = rowptr[wid + 1];
    float ax = 0.f, ay = 0.f;
    const int f = lane << 1;
    int j = beg;
    for (; j + 1 < end; j += 2) {
        int s0 = colv[j], s1 = colv[j + 1];
        float2 v0 = *(const float2*)&feat[(size_t)s0 * D_DIM + f];
        float2 v1 = *(const float2*)&feat[(size_t)s1 * D_DIM + f];
        ax += v0.x; ay += v0.y;
        ax += v1.x; ay += v1.y;
    }
    if (j < end) {
        int s0 = colv[j];
        float2 v0 = *(const float2*)&feat[(size_t)s0 * D_DIM + f];
        ax += v0.x; ay += v0.y;
    }
    float inv = 1.f / fmaxf((float)(end - beg), 1.f);
    ax *= inv; ay *= inv;
    if (addv) { float2 v = *(const float2*)&addv[(size_t)wid * D_DIM + f]; ax += v.x; ay += v.y; }
    if (bias) { float2 v = *(const float2*)&bias[f]; ax += v.x; ay += v.y; }
    if (do_relu) { ax = fmaxf(ax, 0.f); ay = fmaxf(ay, 0.f); }
    *(float2*)&out[(size_t)wid * D_DIM + f] = make_float2(ax, ay);
    if (ohi) {
        ushort h0 = f2bf_rne(ax), h1 = f2bf_rne(ay);
        ushort l0 = f2bf_rne(ax - bf2f(h0)), l1 = f2bf_rne(ay - bf2f(h1));
        *(ushort2*)&ohi[(size_t)wid * D_DIM + f] = make_ushort2(h0, h1);
        *(ushort2*)&olo[(size_t)wid * D_DIM + f] = make_ushort2(l0, l1);
    }
}

// ---------------------------------------------------------------------------
// Up-sweep: down_src = arange(N0) -> exactly one up-edge per lv0 node, so
// plain stores (no atomics, no zero-init). One wave per edge, float2/lane.
// ---------------------------------------------------------------------------
__global__ __launch_bounds__(256) void upscatter_kernel(
    const float* __restrict__ Cb, const float* __restrict__ Db,   // [N1,128]
    const float* __restrict__ Ab, const float* __restrict__ Bb,   // [N0,128]
    const int* __restrict__ dsrc, const int* __restrict__ ddst,
    float* __restrict__ y2s, float* __restrict__ y2n, int E) {
    int gt = blockIdx.x * blockDim.x + threadIdx.x;
    int wid = gt >> 6;
    int lane = threadIdx.x & 63;
    if (wid >= E) return;
    int n = dsrc[wid], c = ddst[wid];
    const int f = lane << 1;
    float2 cv = *(const float2*)&Cb[(size_t)c * D_DIM + f];
    float2 av = *(const float2*)&Ab[(size_t)n * D_DIM + f];
    float2 dv = *(const float2*)&Db[(size_t)c * D_DIM + f];
    float2 bv = *(const float2*)&Bb[(size_t)n * D_DIM + f];
    *(float2*)&y2s[(size_t)n * D_DIM + f] = make_float2(cv.x + av.x, cv.y + av.y);
    *(float2*)&y2n[(size_t)n * D_DIM + f] = make_float2(dv.x + bv.x, dv.y + bv.y);
}

// ---------------------------------------------------------------------------
// Readout + softmax over nodes
// ---------------------------------------------------------------------------
__global__ __launch_bounds__(256) void readout_kernel(
    const float* __restrict__ x0f, const float* __restrict__ Wm,
    const float* __restrict__ bm, float* __restrict__ z, int N) {
    int gt = blockIdx.x * blockDim.x + threadIdx.x;
    int wid = gt >> 6;
    int lane = threadIdx.x & 63;
    if (wid >= N) return;
    const int f = lane << 1;
    float2 v = *(const float2*)&x0f[(size_t)wid * D_DIM + f];
    float2 w = *(const float2*)&Wm[f];
    float p = v.x * w.x + v.y * w.y;
    #pragma unroll
    for (int off = 32; off > 0; off >>= 1) p += __shfl_down(p, off);
    if (lane == 0) z[wid] = p + bm[0];
}

__global__ __launch_bounds__(1024) void softmax_reduce_kernel(
    const float* __restrict__ z, float* __restrict__ red, int N) {
    __shared__ float s[1024];
    int t = threadIdx.x;
    float m = -1e30f;
    for (int i = t; i < N; i += 1024) m = fmaxf(m, z[i]);
    s[t] = m; __syncthreads();
    for (int off = 512; off > 0; off >>= 1) {
        if (t < off) s[t] = fmaxf(s[t], s[t + off]);
        __syncthreads();
    }
    float mx = s[0]; __syncthreads();
    float sum = 0.f;
    for (int i = t; i < N; i += 1024) sum += expf(z[i] - mx);
    s[t] = sum; __syncthreads();
    for (int off = 512; off > 0; off >>= 1) {
        if (t < off) s[t] += s[t + off];
        __syncthreads();
    }
    if (t == 0) { red[0] = mx; red[1] = s[0]; }
}

__global__ __launch_bounds__(256) void softmax_final_kernel(
    const float* __restrict__ z, const float* __restrict__ red,
    float* __restrict__ out, int N) {
    int i = blockIdx.x * blockDim.x + threadIdx.x;
    if (i < N) out[i] = expf(z[i] - red[0]) / red[1];
}

// ---------------------------------------------------------------------------
// Host launcher
// ---------------------------------------------------------------------------
static inline char* align_up(char* p, size_t a) {
    return (char*)(((uintptr_t)p + a - 1) & ~(uintptr_t)(a - 1));
}

extern "C" void kernel_launch(void* const* d_in, const int* in_sizes, int n_in,
                              void* d_out, int out_size, void* d_ws, size_t ws_size,
                              hipStream_t stream) {
    const int N0 = N0_C, N1 = N1_C, E0 = E0_C, E1 = E1_C;
    const float* X   = (const float*)d_in[0];
    const float* W0s = (const float*)d_in[1];
    const float* W0n = (const float*)d_in[2];
    const float* b0  = (const float*)d_in[3];
    const float* W1s = (const float*)d_in[4];
    const float* W1n = (const float*)d_in[5];
    const float* b1  = (const float*)d_in[6];
    const float* W2s = (const float*)d_in[7];
    const float* W2n = (const float*)d_in[8];
    const float* b2  = (const float*)d_in[9];
    const float* Wm  = (const float*)d_in[10];
    const float* bm  = (const float*)d_in[11];
    const int* src0  = (const int*)d_in[12];
    const int* dst0  = (const int*)d_in[13];
    const int* src1  = (const int*)d_in[14];
    const int* dst1  = (const int*)d_in[15];
    const int* dsrc  = (const int*)d_in[16];
    const int* ddst  = (const int*)d_in[17];
    float* out = (float*)d_out;

    char* p = (char*)d_ws;
    const size_t FB = (size_t)N0 * D_DIM;
    const size_t SB = (size_t)N1 * D_DIM;
    auto grab_f = [&](size_t nf) { p = align_up(p, 256); float* r = (float*)p; p += nf * 4; return r; };
    auto grab_i = [&](size_t ni) { p = align_up(p, 256); int* r = (int*)p; p += ni * 4; return r; };
    auto grab_u = [&](size_t nu) { p = align_up(p, 256); ushort* r = (ushort*)p; p += nu * 2; return r; };

    float* bufA = grab_f(FB);   // y0s -> x0
    float* bufB = grab_f(FB);   // y0n -> A2
    float* bufC = grab_f(FB);   // B2
    float* bufD = grab_f(FB);   // y2s -> x0f
    float* bufE = grab_f(FB);   // y2n
    float* x1b  = grab_f(SB);
    float* y1s  = grab_f(SB);   // -> x1f
    float* y1n  = grab_f(SB);
    float* C2   = grab_f(SB);
    float* D2   = grab_f(SB);
    float* zbuf = grab_f(N0);
    float* red  = grab_f(8);
    ushort* P0hi = grab_u(FB);  // X planes, then reused for x0 planes
    ushort* P0lo = grab_u(FB);
    ushort* x1bhi = grab_u(SB);
    ushort* x1blo = grab_u(SB);
    ushort* x1fhi = grab_u(SB);
    ushort* x1flo = grab_u(SB);
    ushort* wt_hi = grab_u(8 * 16384);
    ushort* wt_lo = grab_u(8 * 16384);
    int* cnt0 = grab_i(N0);     // cnt0,cnt1,cntD contiguous -> single memset
    int* cnt1 = (int*)(((char*)cnt0) + (size_t)N0 * 4);
    int* cntD = (int*)(((char*)cnt1) + (size_t)N1 * 4);
    p = (char*)(cntD + N1);
    int* rowptr0 = grab_i(N0 + 1);
    int* rowptr1 = grab_i(N1 + 1);
    int* rowptrD = grab_i(N1 + 1);
    int* col0 = grab_i(E0);
    int* col1 = grab_i(E1);
    int* colD = grab_i(N0);
    (void)ws_size; (void)n_in; (void)in_sizes; (void)out_size;

    const int BT = 256;
    auto cdiv = [](int a, int b) { return (a + b - 1) / b; };
    auto WT_HI = [&](int mi) { return wt_hi + ((size_t)mi << 14); };
    auto WT_LO = [&](int mi) { return wt_lo + ((size_t)mi << 14); };

    // ---- CSR build ----
    hipMemsetAsync(cnt0, 0, (size_t)(N0 + 2 * N1) * 4, stream);
    hist_kernel<<<cdiv(E0, BT), BT, 0, stream>>>(dst0, cnt0, E0);
    hist_kernel<<<cdiv(E1, BT), BT, 0, stream>>>(dst1, cnt1, E1);
    hist_kernel<<<cdiv(N0, BT), BT, 0, stream>>>(ddst, cntD, N0);
    exscan_kernel<<<1, 1024, 0, stream>>>(cnt0, rowptr0, N0);
    exscan_kernel<<<1, 1024, 0, stream>>>(cnt1, rowptr1, N1);
    exscan_kernel<<<1, 1024, 0, stream>>>(cntD, rowptrD, N1);
    hipMemsetAsync(cnt0, 0, (size_t)(N0 + 2 * N1) * 4, stream);
    fill_kernel<<<cdiv(E0, BT), BT, 0, stream>>>(src0, dst0, rowptr0, cnt0, col0, E0);
    fill_kernel<<<cdiv(E1, BT), BT, 0, stream>>>(src1, dst1, rowptr1, cnt1, col1, E1);
    fill_kernel<<<cdiv(N0, BT), BT, 0, stream>>>(dsrc, ddst, rowptrD, cntD, colD, N0);

    // ---- weight prep + X conversion ----
    wprep_kernel<<<512, BT, 0, stream>>>(W0s, W0n, W1s, W1n, W2s, W2n, wt_hi, wt_lo);
    tobf16_kernel<<<cdiv(N0 * 64, BT), BT, 0, stream>>>(X, P0hi, P0lo, N0 * 64);

    // ---- layer 0 SAGE: x0 = X@W0s + b0 + mean_nbr(X@W0n) ----
    dualmm_mfma_kernel<<<cdiv(N0, 64), BT, 0, stream>>>(P0hi, P0lo,
        WT_HI(0), WT_LO(0), WT_HI(1), WT_LO(1), b0, bufA, bufB, N0);
    csr_agg_kernel<<<cdiv(N0, 4), BT, 0, stream>>>(bufB, rowptr0, col0, bufA, nullptr,
        bufA, P0hi, P0lo, N0, 0);   // x0 fp32 + planes (X planes dead now)

    // ---- down pool: x1 = relu(mean_cluster(x0)) ----
    csr_agg_kernel<<<cdiv(N1, 4), BT, 0, stream>>>(bufA, rowptrD, colD, nullptr, nullptr,
        x1b, x1bhi, x1blo, N1, 1);

    // ---- layer 1 SAGE ----
    dualmm_mfma_kernel<<<cdiv(N1, 64), BT, 0, stream>>>(x1bhi, x1blo,
        WT_HI(2), WT_LO(2), WT_HI(3), WT_LO(3), b1, y1s, y1n, N1);
    csr_agg_kernel<<<cdiv(N1, 4), BT, 0, stream>>>(y1n, rowptr1, col1, y1s, nullptr,
        y1s, x1fhi, x1flo, N1, 1);

    // ---- layer 2 per-node matmuls (linearity) ----
    dualmm_mfma_kernel<<<cdiv(N0, 64), BT, 0, stream>>>(P0hi, P0lo,
        WT_HI(5), WT_LO(5), WT_HI(7), WT_LO(7), nullptr, bufB, bufC, N0);
    dualmm_mfma_kernel<<<cdiv(N1, 64), BT, 0, stream>>>(x1fhi, x1flo,
        WT_HI(4), WT_LO(4), WT_HI(6), WT_LO(6), nullptr, C2, D2, N1);

    // ---- up-sweep (injective down_src: plain stores) ----
    upscatter_kernel<<<cdiv(N0, 4), BT, 0, stream>>>(C2, D2, bufB, bufC, dsrc, ddst,
        bufD, bufE, N0);

    // ---- layer 2 SAGE combine ----
    csr_agg_kernel<<<cdiv(N0, 4), BT, 0, stream>>>(bufE, rowptr0, col0, bufD, b2,
        bufD, nullptr, nullptr, N0, 1);

    // ---- readout + softmax ----
    readout_kernel<<<cdiv(N0, 4), BT, 0, stream>>>(bufD, Wm, bm, zbuf, N0);
    softmax_reduce_kernel<<<1, 1024, 0, stream>>>(zbuf, red, N0);
    softmax_final_kernel<<<cdiv(N0, BT), BT, 0, stream>>>(zbuf, red, out, N0);
}

// Round 3
// 464.186 us; speedup vs baseline: 1.6813x; 1.2470x over previous
//
#include <hip/hip_runtime.h>
#include <hip/hip_bf16.h>
#include <cstdint>

#define D_DIM 128
#define N0_C 50000
#define N1_C 5000
#define E0_C 800000
#define E1_C 80000

typedef __attribute__((ext_vector_type(8))) short bf16x8;
typedef __attribute__((ext_vector_type(4))) float f32x4;

__device__ __forceinline__ ushort f2bf_rne(float x) {
    unsigned int u = __float_as_uint(x);
    return (ushort)((u + 0x7FFFu + ((u >> 16) & 1u)) >> 16);
}
__device__ __forceinline__ float bf2f(ushort h) {
    return __uint_as_float(((unsigned int)h) << 16);
}

// ---------------------------------------------------------------------------
// CSR build: histogram -> 3-phase scan (single concatenated array) -> fill
// ---------------------------------------------------------------------------
__global__ __launch_bounds__(256) void hist_kernel(const int* __restrict__ dst,
                                                   int* __restrict__ cnt, int E) {
    int e = blockIdx.x * blockDim.x + threadIdx.x;
    if (e < E) atomicAdd(&cnt[dst[e]], 1);
}

// phase 1: per-block (1024 elems) partial sums
__global__ __launch_bounds__(256) void scan_partial_kernel(
    const int* __restrict__ cnt, int* __restrict__ bsum, int n) {
    __shared__ int ws[4];
    int b = blockIdx.x, t = threadIdx.x, lane = t & 63, w = t >> 6;
    int base = b * 1024 + t * 4;
    int s = 0;
    if (base + 3 < n) { int4 q = *(const int4*)&cnt[base]; s = q.x + q.y + q.z + q.w; }
    else { for (int i = 0; i < 4; ++i) if (base + i < n) s += cnt[base + i]; }
    #pragma unroll
    for (int off = 32; off; off >>= 1) s += __shfl_down(s, off);
    if (lane == 0) ws[w] = s;
    __syncthreads();
    if (t == 0) bsum[b] = ws[0] + ws[1] + ws[2] + ws[3];
}

// phase 2: single-block exclusive scan of block partials (n small)
__global__ __launch_bounds__(1024) void exscan_kernel(const int* __restrict__ cnt,
                                                      int* __restrict__ rowptr, int n) {
    __shared__ int wsum[17];
    __shared__ int base_s;
    const int t = threadIdx.x;
    const int lane = t & 63;
    const int w = t >> 6;
    if (t == 0) { base_s = 0; rowptr[0] = 0; }
    __syncthreads();
    for (int i0 = 0; i0 < n; i0 += 1024) {
        int i = i0 + t;
        int v = (i < n) ? cnt[i] : 0;
        int x = v;
        #pragma unroll
        for (int off = 1; off < 64; off <<= 1) {
            int y = __shfl_up(x, off);
            if (lane >= off) x += y;
        }
        if (lane == 63) wsum[w] = x;
        __syncthreads();
        if (t == 0) {
            int run = base_s;
            #pragma unroll
            for (int j = 0; j < 16; ++j) { int c = wsum[j]; wsum[j] = run; run += c; }
            wsum[16] = run;
        }
        __syncthreads();
        if (i < n) rowptr[i + 1] = wsum[w] + x;
        __syncthreads();
        if (t == 0) base_s = wsum[16];
        __syncthreads();
    }
}

// phase 3: intra-block scan + block offset -> inclusive rowptr[i+1]
__global__ __launch_bounds__(256) void scan_final_kernel(
    const int* __restrict__ cnt, const int* __restrict__ boff,
    int* __restrict__ rowptr, int n) {
    __shared__ int wsum[4];
    int b = blockIdx.x, t = threadIdx.x, lane = t & 63, w = t >> 6;
    int base = b * 1024 + t * 4;
    int v0 = 0, v1 = 0, v2 = 0, v3 = 0;
    if (base + 3 < n) { int4 q = *(const int4*)&cnt[base]; v0 = q.x; v1 = q.y; v2 = q.z; v3 = q.w; }
    else {
        if (base + 0 < n) v0 = cnt[base + 0];
        if (base + 1 < n) v1 = cnt[base + 1];
        if (base + 2 < n) v2 = cnt[base + 2];
        if (base + 3 < n) v3 = cnt[base + 3];
    }
    int s = v0 + v1 + v2 + v3;
    int x = s;
    #pragma unroll
    for (int off = 1; off < 64; off <<= 1) {
        int y = __shfl_up(x, off);
        if (lane >= off) x += y;
    }
    if (lane == 63) wsum[w] = x;
    __syncthreads();
    if (t == 0) { int run = 0; for (int i = 0; i < 4; ++i) { int c = wsum[i]; wsum[i] = run; run += c; } }
    __syncthreads();
    int run = boff[b] + wsum[w] + x - s;
    if (base + 0 < n) { run += v0; rowptr[base + 1] = run; }
    if (base + 1 < n) { run += v1; rowptr[base + 2] = run; }
    if (base + 2 < n) { run += v2; rowptr[base + 3] = run; }
    if (base + 3 < n) { run += v3; rowptr[base + 4] = run; }
    if (b == 0 && t == 0) rowptr[0] = 0;
}

__global__ __launch_bounds__(256) void fill_kernel(const int* __restrict__ src,
                                                   const int* __restrict__ dst,
                                                   const int* __restrict__ rowptr,
                                                   int rbase,
                                                   int* __restrict__ cursor,
                                                   int* __restrict__ colv, int E) {
    int e = blockIdx.x * blockDim.x + threadIdx.x;
    if (e < E) {
        int d = dst[e];
        int p = atomicAdd(&cursor[d], 1);
        colv[rowptr[d] - rbase + p] = src[e];
    }
}

// ---------------------------------------------------------------------------
// Weight prep: 8 logical 128x128 matrices -> W^T hi/lo bf16 planes [n][k]
// mats: 0:W0s 1:W0n 2:W1s 3:W1n 4:W2s_top 5:W2s_bot 6:W2n_top 7:W2n_bot
// ---------------------------------------------------------------------------
__global__ __launch_bounds__(256) void wprep_kernel(
    const float* __restrict__ W0s, const float* __restrict__ W0n,
    const float* __restrict__ W1s, const float* __restrict__ W1n,
    const float* __restrict__ W2s, const float* __restrict__ W2n,
    ushort* __restrict__ wt_hi, ushort* __restrict__ wt_lo) {
    int gi = blockIdx.x * 256 + threadIdx.x;
    int mi = gi >> 14, idx = gi & 16383;
    int k = idx >> 7, n = idx & 127;
    const float* src; int row = k;
    switch (mi) {
        case 0: src = W0s; break;
        case 1: src = W0n; break;
        case 2: src = W1s; break;
        case 3: src = W1n; break;
        case 4: src = W2s; break;
        case 5: src = W2s; row = k + 128; break;
        case 6: src = W2n; break;
        default: src = W2n; row = k + 128; break;
    }
    float v = src[row * 128 + n];
    ushort h = f2bf_rne(v);
    ushort l = f2bf_rne(v - bf2f(h));
    wt_hi[(mi << 14) + n * 128 + k] = h;
    wt_lo[(mi << 14) + n * 128 + k] = l;
}

// ---------------------------------------------------------------------------
// Split-bf16 MFMA dual GEMM, fp32 A (in-register hi/lo split).
// O1 = A@W1 (+bias1) (+C2[ddst[r]]), O2 = A@W2 (+D2[ddst[r]])
// Block 256 thr = 4 waves, 64 rows/block; W^T k-slabs staged in LDS.
// ---------------------------------------------------------------------------
__global__ __launch_bounds__(256) void dualmm_mfma_kernel(
    const float* __restrict__ A,
    const ushort* __restrict__ w1hi, const ushort* __restrict__ w1lo,
    const ushort* __restrict__ w2hi, const ushort* __restrict__ w2lo,
    const float* __restrict__ bias1,
    const int* __restrict__ ddst,                     // null -> no gather-add
    const float* __restrict__ C2g, const float* __restrict__ D2g,
    float* __restrict__ O1, float* __restrict__ O2, int N) {
    __shared__ __align__(16) ushort wslab[4][128][40];
    const int tid = threadIdx.x;
    const int wave = tid >> 6, lane = tid & 63;
    const int m = lane & 15, quad = lane >> 4;
    const int r0 = blockIdx.x * 64 + wave * 16;
    const f32x4 zero = {0.f, 0.f, 0.f, 0.f};
    f32x4 acc1[8], acc2[8];
    #pragma unroll
    for (int ct = 0; ct < 8; ++ct) { acc1[ct] = zero; acc2[ct] = zero; }

    const ushort* wp[4] = {w1hi, w1lo, w2hi, w2lo};
    int ar = r0 + m; if (ar >= N) ar = N - 1;

    for (int c = 0; c < 4; ++c) {
        const int k0 = c * 32;
        if (c) __syncthreads();
        #pragma unroll
        for (int p = 0; p < 4; ++p) {
            const ushort* w = wp[p];
            #pragma unroll
            for (int i = 0; i < 2; ++i) {
                int idx = tid + i * 256;
                int row = idx >> 2, ko = (idx & 3) * 8;
                uint4 v = *(const uint4*)(w + row * 128 + k0 + ko);
                *(uint4*)&wslab[p][row][ko] = v;
            }
        }
        __syncthreads();
        const float* arow = A + (size_t)ar * 128 + k0 + quad * 8;
        float4 a0 = *(const float4*)arow;
        float4 a1 = *(const float4*)(arow + 4);
        float av[8] = {a0.x, a0.y, a0.z, a0.w, a1.x, a1.y, a1.z, a1.w};
        bf16x8 afh, afl;
        #pragma unroll
        for (int i = 0; i < 8; ++i) {
            ushort h = f2bf_rne(av[i]);
            ushort l = f2bf_rne(av[i] - bf2f(h));
            afh[i] = (short)h; afl[i] = (short)l;
        }
        #pragma unroll
        for (int ct = 0; ct < 8; ++ct) {
            const int n = ct * 16 + m;
            bf16x8 b1h = *(const bf16x8*)&wslab[0][n][quad * 8];
            bf16x8 b1l = *(const bf16x8*)&wslab[1][n][quad * 8];
            bf16x8 b2h = *(const bf16x8*)&wslab[2][n][quad * 8];
            bf16x8 b2l = *(const bf16x8*)&wslab[3][n][quad * 8];
            acc1[ct] = __builtin_amdgcn_mfma_f32_16x16x32_bf16(afh, b1h, acc1[ct], 0, 0, 0);
            acc1[ct] = __builtin_amdgcn_mfma_f32_16x16x32_bf16(afl, b1h, acc1[ct], 0, 0, 0);
            acc1[ct] = __builtin_amdgcn_mfma_f32_16x16x32_bf16(afh, b1l, acc1[ct], 0, 0, 0);
            acc2[ct] = __builtin_amdgcn_mfma_f32_16x16x32_bf16(afh, b2h, acc2[ct], 0, 0, 0);
            acc2[ct] = __builtin_amdgcn_mfma_f32_16x16x32_bf16(afl, b2h, acc2[ct], 0, 0, 0);
            acc2[ct] = __builtin_amdgcn_mfma_f32_16x16x32_bf16(afh, b2l, acc2[ct], 0, 0, 0);
        }
    }
    // epilogue: C/D layout col=lane&15, row=quad*4+reg
    int rr[4], cc[4];
    #pragma unroll
    for (int reg = 0; reg < 4; ++reg) {
        rr[reg] = r0 + quad * 4 + reg;
        cc[reg] = (ddst && rr[reg] < N) ? ddst[rr[reg]] : 0;
    }
    #pragma unroll
    for (int ct = 0; ct < 8; ++ct) {
        const int col = ct * 16 + m;
        float bv = bias1 ? bias1[col] : 0.f;
        #pragma unroll
        for (int reg = 0; reg < 4; ++reg) {
            int r = rr[reg];
            if (r < N) {
                float g1 = ddst ? C2g[(size_t)cc[reg] * D_DIM + col] : 0.f;
                float g2 = ddst ? D2g[(size_t)cc[reg] * D_DIM + col] : 0.f;
                O1[(size_t)r * D_DIM + col] = acc1[ct][reg] + bv + g1;
                O2[(size_t)r * D_DIM + col] = acc2[ct][reg] + g2;
            }
        }
    }
}

// ---------------------------------------------------------------------------
// CSR gather-aggregate v2: one wave per dst node, float4/lane => 2 rows per
// load instruction, 4 loads (8 edges) in flight. Optional fused readout.
// ---------------------------------------------------------------------------
__global__ __launch_bounds__(256) void csr_agg2_kernel(
    const float* __restrict__ feat, const int* __restrict__ rowptr, int rbase,
    const int* __restrict__ colv, const float* __restrict__ addv,
    const float* __restrict__ bias, float* __restrict__ out,
    const float* __restrict__ Wm, const float* __restrict__ bm,
    float* __restrict__ z, int Ndst, int do_relu) {
    int gt = blockIdx.x * blockDim.x + threadIdx.x;
    int wid = gt >> 6;
    if (wid >= Ndst) return;
    int lane = threadIdx.x & 63;
    int half = lane >> 5, li = lane & 31;
    const int f4 = li * 4;
    float4 acc = make_float4(0.f, 0.f, 0.f, 0.f);
    int beg = rowptr[wid] - rbase, end = rowptr[wid + 1] - rbase;
    int deg = end - beg;
    int j = beg + half;
    for (; j + 6 < end; j += 8) {
        int r0 = colv[j], r1 = colv[j + 2], r2 = colv[j + 4], r3 = colv[j + 6];
        float4 v0 = *(const float4*)&feat[(size_t)r0 * D_DIM + f4];
        float4 v1 = *(const float4*)&feat[(size_t)r1 * D_DIM + f4];
        float4 v2 = *(const float4*)&feat[(size_t)r2 * D_DIM + f4];
        float4 v3 = *(const float4*)&feat[(size_t)r3 * D_DIM + f4];
        acc.x += v0.x + v1.x + v2.x + v3.x;
        acc.y += v0.y + v1.y + v2.y + v3.y;
        acc.z += v0.z + v1.z + v2.z + v3.z;
        acc.w += v0.w + v1.w + v2.w + v3.w;
    }
    for (; j < end; j += 2) {
        int r = colv[j];
        float4 v = *(const float4*)&feat[(size_t)r * D_DIM + f4];
        acc.x += v.x; acc.y += v.y; acc.z += v.z; acc.w += v.w;
    }
    // combine halves (each half holds sums over its edge subset)
    acc.x += __shfl_xor(acc.x, 32);
    acc.y += __shfl_xor(acc.y, 32);
    acc.z += __shfl_xor(acc.z, 32);
    acc.w += __shfl_xor(acc.w, 32);
    float invd = 1.f / fmaxf((float)deg, 1.f);
    acc.x *= invd; acc.y *= invd; acc.z *= invd; acc.w *= invd;
    if (addv) {
        float4 v = *(const float4*)&addv[(size_t)wid * D_DIM + f4];
        acc.x += v.x; acc.y += v.y; acc.z += v.z; acc.w += v.w;
    }
    if (bias) {
        float4 v = *(const float4*)&bias[f4];
        acc.x += v.x; acc.y += v.y; acc.z += v.z; acc.w += v.w;
    }
    if (do_relu) {
        acc.x = fmaxf(acc.x, 0.f); acc.y = fmaxf(acc.y, 0.f);
        acc.z = fmaxf(acc.z, 0.f); acc.w = fmaxf(acc.w, 0.f);
    }
    if (out && half == 0)
        *(float4*)&out[(size_t)wid * D_DIM + f4] = acc;
    if (z) {
        float4 w = *(const float4*)&Wm[f4];
        float p = acc.x * w.x + acc.y * w.y + acc.z * w.z + acc.w * w.w;
        if (half) p = 0.f;
        #pragma unroll
        for (int off = 32; off > 0; off >>= 1) p += __shfl_down(p, off);
        if (lane == 0) z[wid] = p + bm[0];
    }
}

// ---------------------------------------------------------------------------
// 2-phase online softmax over z[N0]
// ---------------------------------------------------------------------------
__global__ __launch_bounds__(256) void softmax_partial_kernel(
    const float* __restrict__ z, float* __restrict__ red, int N, int nblk) {
    __shared__ float sm[4], ss[4];
    int t = threadIdx.x, b = blockIdx.x;
    int lane = t & 63, w = t >> 6;
    float m = -1e30f, s = 0.f;
    for (int i = b * 256 + t; i < N; i += nblk * 256) {
        float v = z[i];
        if (v > m) { s = s * __expf(m - v) + 1.f; m = v; }
        else s += __expf(v - m);
    }
    #pragma unroll
    for (int off = 32; off > 0; off >>= 1) {
        float mo = __shfl_down(m, off), so = __shfl_down(s, off);
        if (mo > m) { s = s * __expf(m - mo) + so; m = mo; }
        else s += so * __expf(mo - m);
    }
    if (lane == 0) { sm[w] = m; ss[w] = s; }
    __syncthreads();
    if (t == 0) {
        for (int i = 1; i < 4; ++i) {
            float mo = sm[i], so = ss[i];
            if (mo > m) { s = s * __expf(m - mo) + so; m = mo; }
            else s += so * __expf(mo - m);
        }
        red[2 + 2 * b] = m; red[3 + 2 * b] = s;
    }
}

__global__ __launch_bounds__(64) void softmax_merge_kernel(float* __restrict__ red, int B) {
    int t = threadIdx.x;
    float m = -1e30f, s = 0.f;
    if (t < B) { m = red[2 + 2 * t]; s = red[3 + 2 * t]; }
    #pragma unroll
    for (int off = 32; off > 0; off >>= 1) {
        float mo = __shfl_down(m, off), so = __shfl_down(s, off);
        if (mo > m) { s = s * __expf(m - mo) + so; m = mo; }
        else s += so * __expf(mo - m);
    }
    if (t == 0) { red[0] = m; red[1] = s; }
}

__global__ __launch_bounds__(256) void softmax_final_kernel(
    const float* __restrict__ z, const float* __restrict__ red,
    float* __restrict__ out, int N) {
    int i = blockIdx.x * blockDim.x + threadIdx.x;
    if (i < N) out[i] = expf(z[i] - red[0]) / red[1];
}

// ---------------------------------------------------------------------------
// Host launcher
// ---------------------------------------------------------------------------
static inline char* align_up(char* p, size_t a) {
    return (char*)(((uintptr_t)p + a - 1) & ~(uintptr_t)(a - 1));
}

extern "C" void kernel_launch(void* const* d_in, const int* in_sizes, int n_in,
                              void* d_out, int out_size, void* d_ws, size_t ws_size,
                              hipStream_t stream) {
    const int N0 = N0_C, N1 = N1_C, E0 = E0_C, E1 = E1_C;
    const float* X   = (const float*)d_in[0];
    const float* W0s = (const float*)d_in[1];
    const float* W0n = (const float*)d_in[2];
    const float* b0  = (const float*)d_in[3];
    const float* W1s = (const float*)d_in[4];
    const float* W1n = (const float*)d_in[5];
    const float* b1  = (const float*)d_in[6];
    const float* W2s = (const float*)d_in[7];
    const float* W2n = (const float*)d_in[8];
    const float* b2  = (const float*)d_in[9];
    const float* Wm  = (const float*)d_in[10];
    const float* bm  = (const float*)d_in[11];
    const int* src0  = (const int*)d_in[12];
    const int* dst0  = (const int*)d_in[13];
    const int* src1  = (const int*)d_in[14];
    const int* dst1  = (const int*)d_in[15];
    const int* dsrc  = (const int*)d_in[16];
    const int* ddst  = (const int*)d_in[17];
    float* out = (float*)d_out;

    char* p = (char*)d_ws;
    const size_t FB = (size_t)N0 * D_DIM;
    const size_t SB = (size_t)N1 * D_DIM;
    auto grab_f = [&](size_t nf) { p = align_up(p, 256); float* r = (float*)p; p += nf * 4; return r; };
    auto grab_i = [&](size_t ni) { p = align_up(p, 256); int* r = (int*)p; p += ni * 4; return r; };
    auto grab_u = [&](size_t nu) { p = align_up(p, 256); ushort* r = (ushort*)p; p += nu * 2; return r; };

    float* bufA = grab_f(FB);   // y0s -> x0
    float* bufB = grab_f(FB);   // y0n
    float* bufD = grab_f(FB);   // y2s
    float* bufE = grab_f(FB);   // y2n
    float* x1b  = grab_f(SB);
    float* y1s  = grab_f(SB);   // -> x1f
    float* y1n  = grab_f(SB);
    float* C2   = grab_f(SB);
    float* D2   = grab_f(SB);
    float* zbuf = grab_f(N0);
    float* red  = grab_f(256);
    ushort* wt_hi = grab_u(8 * 16384);
    ushort* wt_lo = grab_u(8 * 16384);
    const int NC = N0 + 2 * N1;            // concatenated count length
    int* cntAll = grab_i(NC);              // [cnt0 | cnt1 | cntD]
    int* rowptrAll = grab_i(NC + 1);
    int* bsum = grab_i(256);
    int* boff = grab_i(256);
    int* col0 = grab_i(E0);
    int* col1 = grab_i(E1);
    int* colD = grab_i(N0);
    (void)ws_size; (void)n_in; (void)in_sizes; (void)out_size;

    const int BT = 256;
    auto cdiv = [](int a, int b) { return (a + b - 1) / b; };
    auto WT_HI = [&](int mi) { return wt_hi + ((size_t)mi << 14); };
    auto WT_LO = [&](int mi) { return wt_lo + ((size_t)mi << 14); };

    // ---- CSR build (one concatenated scan for all three graphs) ----
    hipMemsetAsync(cntAll, 0, (size_t)NC * 4, stream);
    hist_kernel<<<cdiv(E0, BT), BT, 0, stream>>>(dst0, cntAll, E0);
    hist_kernel<<<cdiv(E1, BT), BT, 0, stream>>>(dst1, cntAll + N0, E1);
    hist_kernel<<<cdiv(N0, BT), BT, 0, stream>>>(ddst, cntAll + N0 + N1, N0);
    const int NB = cdiv(NC, 1024);
    scan_partial_kernel<<<NB, BT, 0, stream>>>(cntAll, bsum, NC);
    exscan_kernel<<<1, 1024, 0, stream>>>(bsum, boff, NB);
    scan_final_kernel<<<NB, BT, 0, stream>>>(cntAll, boff, rowptrAll, NC);
    hipMemsetAsync(cntAll, 0, (size_t)NC * 4, stream);
    fill_kernel<<<cdiv(E0, BT), BT, 0, stream>>>(src0, dst0, rowptrAll, 0, cntAll, col0, E0);
    fill_kernel<<<cdiv(E1, BT), BT, 0, stream>>>(src1, dst1, rowptrAll + N0, E0, cntAll + N0, col1, E1);
    fill_kernel<<<cdiv(N0, BT), BT, 0, stream>>>(dsrc, ddst, rowptrAll + N0 + N1, E0 + E1,
                                                 cntAll + N0 + N1, colD, N0);

    // ---- weight prep ----
    wprep_kernel<<<512, BT, 0, stream>>>(W0s, W0n, W1s, W1n, W2s, W2n, wt_hi, wt_lo);

    // ---- layer 0 SAGE: x0 = X@W0s + b0 + mean_nbr(X@W0n) ----
    dualmm_mfma_kernel<<<cdiv(N0, 64), BT, 0, stream>>>(X,
        WT_HI(0), WT_LO(0), WT_HI(1), WT_LO(1), b0, nullptr, nullptr, nullptr,
        bufA, bufB, N0);
    csr_agg2_kernel<<<cdiv(N0, 4), BT, 0, stream>>>(bufB, rowptrAll, 0, col0, bufA,
        nullptr, bufA, nullptr, nullptr, nullptr, N0, 0);

    // ---- down pool: x1 = relu(mean_cluster(x0)) ----
    csr_agg2_kernel<<<cdiv(N1, 4), BT, 0, stream>>>(bufA, rowptrAll + N0 + N1, E0 + E1,
        colD, nullptr, nullptr, x1b, nullptr, nullptr, nullptr, N1, 1);

    // ---- layer 1 SAGE: x1f = relu(x1@W1s + b1 + mean_nbr(x1@W1n)) ----
    dualmm_mfma_kernel<<<cdiv(N1, 64), BT, 0, stream>>>(x1b,
        WT_HI(2), WT_LO(2), WT_HI(3), WT_LO(3), b1, nullptr, nullptr, nullptr,
        y1s, y1n, N1);
    csr_agg2_kernel<<<cdiv(N1, 4), BT, 0, stream>>>(y1n, rowptrAll + N0, E0, col1, y1s,
        nullptr, y1s, nullptr, nullptr, nullptr, N1, 1);

    // ---- layer 2: small dualmm (C2/D2), then big dualmm with fused up-scatter ----
    dualmm_mfma_kernel<<<cdiv(N1, 64), BT, 0, stream>>>(y1s,
        WT_HI(4), WT_LO(4), WT_HI(6), WT_LO(6), nullptr, nullptr, nullptr, nullptr,
        C2, D2, N1);
    dualmm_mfma_kernel<<<cdiv(N0, 64), BT, 0, stream>>>(bufA,
        WT_HI(5), WT_LO(5), WT_HI(7), WT_LO(7), nullptr, ddst, C2, D2,
        bufD, bufE, N0);

    // ---- layer 2 combine + fused readout: z = relu(y2s+b2+mean(y2n)) @ Wm + bm ----
    csr_agg2_kernel<<<cdiv(N0, 4), BT, 0, stream>>>(bufE, rowptrAll, 0, col0, bufD,
        b2, nullptr, Wm, bm, zbuf, N0, 1);

    // ---- softmax over nodes ----
    softmax_partial_kernel<<<64, BT, 0, stream>>>(zbuf, red, N0, 64);
    softmax_merge_kernel<<<1, 64, 0, stream>>>(red, 64);
    softmax_final_kernel<<<cdiv(N0, BT), BT, 0, stream>>>(zbuf, red, out, N0);
}

// Round 4
// 410.373 us; speedup vs baseline: 1.9018x; 1.1311x over previous
//
#include <hip/hip_runtime.h>
#include <hip/hip_bf16.h>
#include <cstdint>

#define D_DIM 128
#define N0_C 50000
#define N1_C 5000
#define E0_C 800000
#define E1_C 80000
#define BIN_SHIFT 9          // 512 dst nodes per bin (graph0 fill)

typedef __attribute__((ext_vector_type(8))) short bf16x8;
typedef __attribute__((ext_vector_type(4))) float f32x4;

__device__ __forceinline__ ushort f2bf_rne(float x) {
    unsigned int u = __float_as_uint(x);
    return (ushort)((u + 0x7FFFu + ((u >> 16) & 1u)) >> 16);
}
__device__ __forceinline__ float bf2f(ushort h) {
    return __uint_as_float(((unsigned int)h) << 16);
}

// ---------------------------------------------------------------------------
// CSR build: histogram -> 3-phase scan (single concatenated array) -> fill
// ---------------------------------------------------------------------------
__global__ __launch_bounds__(256) void hist_kernel(const int* __restrict__ dst,
                                                   int* __restrict__ cnt, int E) {
    int e = blockIdx.x * blockDim.x + threadIdx.x;
    if (e < E) atomicAdd(&cnt[dst[e]], 1);
}

__global__ __launch_bounds__(256) void scan_partial_kernel(
    const int* __restrict__ cnt, int* __restrict__ bsum, int n) {
    __shared__ int ws[4];
    int b = blockIdx.x, t = threadIdx.x, lane = t & 63, w = t >> 6;
    int base = b * 1024 + t * 4;
    int s = 0;
    if (base + 3 < n) { int4 q = *(const int4*)&cnt[base]; s = q.x + q.y + q.z + q.w; }
    else { for (int i = 0; i < 4; ++i) if (base + i < n) s += cnt[base + i]; }
    #pragma unroll
    for (int off = 32; off; off >>= 1) s += __shfl_down(s, off);
    if (lane == 0) ws[w] = s;
    __syncthreads();
    if (t == 0) bsum[b] = ws[0] + ws[1] + ws[2] + ws[3];
}

__global__ __launch_bounds__(1024) void exscan_kernel(const int* __restrict__ cnt,
                                                      int* __restrict__ rowptr, int n) {
    __shared__ int wsum[17];
    __shared__ int base_s;
    const int t = threadIdx.x;
    const int lane = t & 63;
    const int w = t >> 6;
    if (t == 0) { base_s = 0; rowptr[0] = 0; }
    __syncthreads();
    for (int i0 = 0; i0 < n; i0 += 1024) {
        int i = i0 + t;
        int v = (i < n) ? cnt[i] : 0;
        int x = v;
        #pragma unroll
        for (int off = 1; off < 64; off <<= 1) {
            int y = __shfl_up(x, off);
            if (lane >= off) x += y;
        }
        if (lane == 63) wsum[w] = x;
        __syncthreads();
        if (t == 0) {
            int run = base_s;
            #pragma unroll
            for (int j = 0; j < 16; ++j) { int c = wsum[j]; wsum[j] = run; run += c; }
            wsum[16] = run;
        }
        __syncthreads();
        if (i < n) rowptr[i + 1] = wsum[w] + x;
        __syncthreads();
        if (t == 0) base_s = wsum[16];
        __syncthreads();
    }
}

__global__ __launch_bounds__(256) void scan_final_kernel(
    const int* __restrict__ cnt, const int* __restrict__ boff,
    int* __restrict__ rowptr, int n) {
    __shared__ int wsum[4];
    int b = blockIdx.x, t = threadIdx.x, lane = t & 63, w = t >> 6;
    int base = b * 1024 + t * 4;
    int v0 = 0, v1 = 0, v2 = 0, v3 = 0;
    if (base + 3 < n) { int4 q = *(const int4*)&cnt[base]; v0 = q.x; v1 = q.y; v2 = q.z; v3 = q.w; }
    else {
        if (base + 0 < n) v0 = cnt[base + 0];
        if (base + 1 < n) v1 = cnt[base + 1];
        if (base + 2 < n) v2 = cnt[base + 2];
        if (base + 3 < n) v3 = cnt[base + 3];
    }
    int s = v0 + v1 + v2 + v3;
    int x = s;
    #pragma unroll
    for (int off = 1; off < 64; off <<= 1) {
        int y = __shfl_up(x, off);
        if (lane >= off) x += y;
    }
    if (lane == 63) wsum[w] = x;
    __syncthreads();
    if (t == 0) { int run = 0; for (int i = 0; i < 4; ++i) { int c = wsum[i]; wsum[i] = run; run += c; } }
    __syncthreads();
    int run = boff[b] + wsum[w] + x - s;
    if (base + 0 < n) { run += v0; rowptr[base + 1] = run; }
    if (base + 1 < n) { run += v1; rowptr[base + 2] = run; }
    if (base + 2 < n) { run += v2; rowptr[base + 3] = run; }
    if (base + 3 < n) { run += v3; rowptr[base + 4] = run; }
    if (b == 0 && t == 0) rowptr[0] = 0;
}

// small-graph fill (scatter window small -> L2-friendly)
__global__ __launch_bounds__(256) void fill_kernel(const int* __restrict__ src,
                                                   const int* __restrict__ dst,
                                                   const int* __restrict__ rowptr,
                                                   int rbase,
                                                   int* __restrict__ cursor,
                                                   int* __restrict__ colv, int E) {
    int e = blockIdx.x * blockDim.x + threadIdx.x;
    if (e < E) {
        int d = dst[e];
        int p = atomicAdd(&cursor[d], 1);
        colv[rowptr[d] - rbase + p] = src[e];
    }
}

// ---- graph0 binned fill: coalesced pair scatter, then windowed colv fill ----
__global__ __launch_bounds__(64) void initcur_kernel(const int* __restrict__ rowptr,
                                                     int* __restrict__ cursors,
                                                     int nbins, int N) {
    int b = blockIdx.x * 64 + threadIdx.x;
    if (b < nbins) {
        int idx = b << BIN_SHIFT; if (idx > N) idx = N;
        cursors[b] = rowptr[idx];
    }
}

__global__ __launch_bounds__(256) void binscatter_kernel(
    const int* __restrict__ src, const int* __restrict__ dstv,
    int* __restrict__ cursors, int2* __restrict__ pairs, int E, int nbins) {
    __shared__ int lcnt[128];
    __shared__ int sbase[128];
    int t = threadIdx.x;
    int e0 = blockIdx.x * 4096;
    if (t < 128) lcnt[t] = 0;
    __syncthreads();
    int lrank[16], dloc[16];
    #pragma unroll
    for (int i = 0; i < 16; ++i) {
        int e = e0 + t + i * 256;
        if (e < E) {
            int d = dstv[e];
            dloc[i] = d;
            lrank[i] = atomicAdd(&lcnt[d >> BIN_SHIFT], 1);
        } else dloc[i] = -1;
    }
    __syncthreads();
    if (t < nbins && lcnt[t] > 0) sbase[t] = atomicAdd(&cursors[t], lcnt[t]);
    __syncthreads();
    #pragma unroll
    for (int i = 0; i < 16; ++i) {
        int e = e0 + t + i * 256;
        if (e < E) {
            int d = dloc[i];
            pairs[sbase[d >> BIN_SHIFT] + lrank[i]] = make_int2(d, src[e]);
        }
    }
}

__global__ __launch_bounds__(256) void binfill_kernel(
    const int2* __restrict__ pairs, const int* __restrict__ rowptr,
    int* __restrict__ colv, int N) {
    __shared__ int rp[513];
    __shared__ int cur[512];
    int b = blockIdx.x, t = threadIdx.x;
    int binbase = b << BIN_SHIFT;
    for (int i = t; i < 513; i += 256) {
        int idx = binbase + i; if (idx > N) idx = N;
        rp[i] = rowptr[idx];
    }
    for (int i = t; i < 512; i += 256) cur[i] = 0;
    __syncthreads();
    int beg = rp[0], end = rp[512];
    for (int i = beg + t; i < end; i += 256) {
        int2 pr = pairs[i];
        int local = pr.x - binbase;
        int rank = atomicAdd(&cur[local], 1);
        colv[rp[local] + rank] = pr.y;
    }
}

// ---------------------------------------------------------------------------
// Weight prep: 8 logical 128x128 matrices -> W^T hi/lo bf16 planes [n][k]
// ---------------------------------------------------------------------------
__global__ __launch_bounds__(256) void wprep_kernel(
    const float* __restrict__ W0s, const float* __restrict__ W0n,
    const float* __restrict__ W1s, const float* __restrict__ W1n,
    const float* __restrict__ W2s, const float* __restrict__ W2n,
    ushort* __restrict__ wt_hi, ushort* __restrict__ wt_lo) {
    int gi = blockIdx.x * 256 + threadIdx.x;
    int mi = gi >> 14, idx = gi & 16383;
    int k = idx >> 7, n = idx & 127;
    const float* src; int row = k;
    switch (mi) {
        case 0: src = W0s; break;
        case 1: src = W0n; break;
        case 2: src = W1s; break;
        case 3: src = W1n; break;
        case 4: src = W2s; break;
        case 5: src = W2s; row = k + 128; break;
        case 6: src = W2n; break;
        default: src = W2n; row = k + 128; break;
    }
    float v = src[row * 128 + n];
    ushort h = f2bf_rne(v);
    ushort l = f2bf_rne(v - bf2f(h));
    wt_hi[(mi << 14) + n * 128 + k] = h;
    wt_lo[(mi << 14) + n * 128 + k] = l;
}

// ---------------------------------------------------------------------------
// Split-bf16 MFMA dual GEMM, fp32 A (in-register hi/lo split).
// O1 = A@W1 (+bias1) (+C2[ddst[r]]),  O2 = A@W2 (+D2[ddst[r]])
// O2 emitted as bf16 if O2b non-null (consumed only by mean-aggregate).
// ---------------------------------------------------------------------------
__global__ __launch_bounds__(256) void dualmm_mfma_kernel(
    const float* __restrict__ A,
    const ushort* __restrict__ w1hi, const ushort* __restrict__ w1lo,
    const ushort* __restrict__ w2hi, const ushort* __restrict__ w2lo,
    const float* __restrict__ bias1,
    const int* __restrict__ ddst,
    const float* __restrict__ C2g, const float* __restrict__ D2g,
    float* __restrict__ O1, float* __restrict__ O2,
    ushort* __restrict__ O2b, int N) {
    __shared__ __align__(16) ushort wslab[4][128][40];
    const int tid = threadIdx.x;
    const int wave = tid >> 6, lane = tid & 63;
    const int m = lane & 15, quad = lane >> 4;
    const int r0 = blockIdx.x * 64 + wave * 16;
    const f32x4 zero = {0.f, 0.f, 0.f, 0.f};
    f32x4 acc1[8], acc2[8];
    #pragma unroll
    for (int ct = 0; ct < 8; ++ct) { acc1[ct] = zero; acc2[ct] = zero; }

    const ushort* wp[4] = {w1hi, w1lo, w2hi, w2lo};
    int ar = r0 + m; if (ar >= N) ar = N - 1;

    for (int c = 0; c < 4; ++c) {
        const int k0 = c * 32;
        if (c) __syncthreads();
        #pragma unroll
        for (int p = 0; p < 4; ++p) {
            const ushort* w = wp[p];
            #pragma unroll
            for (int i = 0; i < 2; ++i) {
                int idx = tid + i * 256;
                int row = idx >> 2, ko = (idx & 3) * 8;
                uint4 v = *(const uint4*)(w + row * 128 + k0 + ko);
                *(uint4*)&wslab[p][row][ko] = v;
            }
        }
        __syncthreads();
        const float* arow = A + (size_t)ar * 128 + k0 + quad * 8;
        float4 a0 = *(const float4*)arow;
        float4 a1 = *(const float4*)(arow + 4);
        float av[8] = {a0.x, a0.y, a0.z, a0.w, a1.x, a1.y, a1.z, a1.w};
        bf16x8 afh, afl;
        #pragma unroll
        for (int i = 0; i < 8; ++i) {
            ushort h = f2bf_rne(av[i]);
            ushort l = f2bf_rne(av[i] - bf2f(h));
            afh[i] = (short)h; afl[i] = (short)l;
        }
        #pragma unroll
        for (int ct = 0; ct < 8; ++ct) {
            const int n = ct * 16 + m;
            bf16x8 b1h = *(const bf16x8*)&wslab[0][n][quad * 8];
            bf16x8 b1l = *(const bf16x8*)&wslab[1][n][quad * 8];
            bf16x8 b2h = *(const bf16x8*)&wslab[2][n][quad * 8];
            bf16x8 b2l = *(const bf16x8*)&wslab[3][n][quad * 8];
            acc1[ct] = __builtin_amdgcn_mfma_f32_16x16x32_bf16(afh, b1h, acc1[ct], 0, 0, 0);
            acc1[ct] = __builtin_amdgcn_mfma_f32_16x16x32_bf16(afl, b1h, acc1[ct], 0, 0, 0);
            acc1[ct] = __builtin_amdgcn_mfma_f32_16x16x32_bf16(afh, b1l, acc1[ct], 0, 0, 0);
            acc2[ct] = __builtin_amdgcn_mfma_f32_16x16x32_bf16(afh, b2h, acc2[ct], 0, 0, 0);
            acc2[ct] = __builtin_amdgcn_mfma_f32_16x16x32_bf16(afl, b2h, acc2[ct], 0, 0, 0);
            acc2[ct] = __builtin_amdgcn_mfma_f32_16x16x32_bf16(afh, b2l, acc2[ct], 0, 0, 0);
        }
    }
    int rr[4], cc[4];
    #pragma unroll
    for (int reg = 0; reg < 4; ++reg) {
        rr[reg] = r0 + quad * 4 + reg;
        cc[reg] = (ddst && rr[reg] < N) ? ddst[rr[reg]] : 0;
    }
    #pragma unroll
    for (int ct = 0; ct < 8; ++ct) {
        const int col = ct * 16 + m;
        float bv = bias1 ? bias1[col] : 0.f;
        #pragma unroll
        for (int reg = 0; reg < 4; ++reg) {
            int r = rr[reg];
            if (r < N) {
                float g1 = ddst ? C2g[(size_t)cc[reg] * D_DIM + col] : 0.f;
                float g2 = ddst ? D2g[(size_t)cc[reg] * D_DIM + col] : 0.f;
                O1[(size_t)r * D_DIM + col] = acc1[ct][reg] + bv + g1;
                float o2v = acc2[ct][reg] + g2;
                if (O2b) O2b[(size_t)r * D_DIM + col] = f2bf_rne(o2v);
                else     O2[(size_t)r * D_DIM + col] = o2v;
            }
        }
    }
}

// ---------------------------------------------------------------------------
// fp32 CSR gather-aggregate (small graphs): wave/node, float4/lane (2 rows/ld)
// ---------------------------------------------------------------------------
__global__ __launch_bounds__(256) void csr_agg2_kernel(
    const float* __restrict__ feat, const int* __restrict__ rowptr, int rbase,
    const int* __restrict__ colv, const float* __restrict__ addv,
    const float* __restrict__ bias, float* __restrict__ out,
    int Ndst, int do_relu) {
    int gt = blockIdx.x * blockDim.x + threadIdx.x;
    int wid = gt >> 6;
    if (wid >= Ndst) return;
    int lane = threadIdx.x & 63;
    int half = lane >> 5, li = lane & 31;
    const int f4 = li * 4;
    float4 acc = make_float4(0.f, 0.f, 0.f, 0.f);
    int beg = rowptr[wid] - rbase, end = rowptr[wid + 1] - rbase;
    int deg = end - beg;
    int j = beg + half;
    for (; j + 6 < end; j += 8) {
        int r0 = colv[j], r1 = colv[j + 2], r2 = colv[j + 4], r3 = colv[j + 6];
        float4 v0 = *(const float4*)&feat[(size_t)r0 * D_DIM + f4];
        float4 v1 = *(const float4*)&feat[(size_t)r1 * D_DIM + f4];
        float4 v2 = *(const float4*)&feat[(size_t)r2 * D_DIM + f4];
        float4 v3 = *(const float4*)&feat[(size_t)r3 * D_DIM + f4];
        acc.x += v0.x + v1.x + v2.x + v3.x;
        acc.y += v0.y + v1.y + v2.y + v3.y;
        acc.z += v0.z + v1.z + v2.z + v3.z;
        acc.w += v0.w + v1.w + v2.w + v3.w;
    }
    for (; j < end; j += 2) {
        int r = colv[j];
        float4 v = *(const float4*)&feat[(size_t)r * D_DIM + f4];
        acc.x += v.x; acc.y += v.y; acc.z += v.z; acc.w += v.w;
    }
    acc.x += __shfl_xor(acc.x, 32);
    acc.y += __shfl_xor(acc.y, 32);
    acc.z += __shfl_xor(acc.z, 32);
    acc.w += __shfl_xor(acc.w, 32);
    float invd = 1.f / fmaxf((float)deg, 1.f);
    acc.x *= invd; acc.y *= invd; acc.z *= invd; acc.w *= invd;
    if (addv) {
        float4 v = *(const float4*)&addv[(size_t)wid * D_DIM + f4];
        acc.x += v.x; acc.y += v.y; acc.z += v.z; acc.w += v.w;
    }
    if (bias) {
        float4 v = *(const float4*)&bias[f4];
        acc.x += v.x; acc.y += v.y; acc.z += v.z; acc.w += v.w;
    }
    if (do_relu) {
        acc.x = fmaxf(acc.x, 0.f); acc.y = fmaxf(acc.y, 0.f);
        acc.z = fmaxf(acc.z, 0.f); acc.w = fmaxf(acc.w, 0.f);
    }
    if (half == 0)
        *(float4*)&out[(size_t)wid * D_DIM + f4] = acc;
}

// ---------------------------------------------------------------------------
// bf16-input CSR gather-aggregate (big graphs): wave/node, uint4(8 bf16)/lane,
// 16 lanes/row -> 4 rows per load instr, 16 edges in flight. fp32 accumulate.
// Optional fused readout  z = relu(...)@Wm + bm.
// ---------------------------------------------------------------------------
__device__ __forceinline__ void acc8_add(float* acc, uint4 r) {
    acc[0] += __uint_as_float(r.x << 16);
    acc[1] += __uint_as_float(r.x & 0xFFFF0000u);
    acc[2] += __uint_as_float(r.y << 16);
    acc[3] += __uint_as_float(r.y & 0xFFFF0000u);
    acc[4] += __uint_as_float(r.z << 16);
    acc[5] += __uint_as_float(r.z & 0xFFFF0000u);
    acc[6] += __uint_as_float(r.w << 16);
    acc[7] += __uint_as_float(r.w & 0xFFFF0000u);
}

__global__ __launch_bounds__(256) void csr_aggb_kernel(
    const ushort* __restrict__ featb, const int* __restrict__ rowptr, int rbase,
    const int* __restrict__ colv, const float* __restrict__ addv,
    const float* __restrict__ bias, float* __restrict__ out,
    const float* __restrict__ Wm, const float* __restrict__ bm,
    float* __restrict__ z, int Ndst, int do_relu) {
    int gt = blockIdx.x * blockDim.x + threadIdx.x;
    int wid = gt >> 6;
    if (wid >= Ndst) return;
    int lane = threadIdx.x & 63;
    int q = lane >> 4, li = lane & 15;
    const int f8 = li * 8;
    float acc[8];
    #pragma unroll
    for (int i = 0; i < 8; ++i) acc[i] = 0.f;
    int beg = rowptr[wid] - rbase, end = rowptr[wid + 1] - rbase;
    int deg = end - beg;
    int j = beg + q;
    for (; j + 12 < end; j += 16) {
        int r0 = colv[j], r1 = colv[j + 4], r2 = colv[j + 8], r3 = colv[j + 12];
        uint4 v0 = *(const uint4*)&featb[(size_t)r0 * D_DIM + f8];
        uint4 v1 = *(const uint4*)&featb[(size_t)r1 * D_DIM + f8];
        uint4 v2 = *(const uint4*)&featb[(size_t)r2 * D_DIM + f8];
        uint4 v3 = *(const uint4*)&featb[(size_t)r3 * D_DIM + f8];
        acc8_add(acc, v0); acc8_add(acc, v1); acc8_add(acc, v2); acc8_add(acc, v3);
    }
    for (; j < end; j += 4) {
        int r = colv[j];
        uint4 v = *(const uint4*)&featb[(size_t)r * D_DIM + f8];
        acc8_add(acc, v);
    }
    #pragma unroll
    for (int i = 0; i < 8; ++i) {
        acc[i] += __shfl_xor(acc[i], 16);
        acc[i] += __shfl_xor(acc[i], 32);
    }
    float invd = 1.f / fmaxf((float)deg, 1.f);
    #pragma unroll
    for (int i = 0; i < 8; ++i) acc[i] *= invd;
    if (addv) {
        float4 a0 = *(const float4*)&addv[(size_t)wid * D_DIM + f8];
        float4 a1 = *(const float4*)&addv[(size_t)wid * D_DIM + f8 + 4];
        acc[0] += a0.x; acc[1] += a0.y; acc[2] += a0.z; acc[3] += a0.w;
        acc[4] += a1.x; acc[5] += a1.y; acc[6] += a1.z; acc[7] += a1.w;
    }
    if (bias) {
        float4 b0 = *(const float4*)&bias[f8];
        float4 b1 = *(const float4*)&bias[f8 + 4];
        acc[0] += b0.x; acc[1] += b0.y; acc[2] += b0.z; acc[3] += b0.w;
        acc[4] += b1.x; acc[5] += b1.y; acc[6] += b1.z; acc[7] += b1.w;
    }
    if (do_relu) {
        #pragma unroll
        for (int i = 0; i < 8; ++i) acc[i] = fmaxf(acc[i], 0.f);
    }
    if (out && q == 0) {
        *(float4*)&out[(size_t)wid * D_DIM + f8] =
            make_float4(acc[0], acc[1], acc[2], acc[3]);
        *(float4*)&out[(size_t)wid * D_DIM + f8 + 4] =
            make_float4(acc[4], acc[5], acc[6], acc[7]);
    }
    if (z) {
        float4 w0 = *(const float4*)&Wm[f8];
        float4 w1 = *(const float4*)&Wm[f8 + 4];
        float p = acc[0] * w0.x + acc[1] * w0.y + acc[2] * w0.z + acc[3] * w0.w
                + acc[4] * w1.x + acc[5] * w1.y + acc[6] * w1.z + acc[7] * w1.w;
        if (q != 0) p = 0.f;
        #pragma unroll
        for (int off = 32; off > 0; off >>= 1) p += __shfl_down(p, off);
        if (lane == 0) z[wid] = p + bm[0];
    }
}

// ---------------------------------------------------------------------------
// 2-phase online softmax over z[N0]
// ---------------------------------------------------------------------------
__global__ __launch_bounds__(256) void softmax_partial_kernel(
    const float* __restrict__ z, float* __restrict__ red, int N, int nblk) {
    __shared__ float sm[4], ss[4];
    int t = threadIdx.x, b = blockIdx.x;
    int lane = t & 63, w = t >> 6;
    float m = -1e30f, s = 0.f;
    for (int i = b * 256 + t; i < N; i += nblk * 256) {
        float v = z[i];
        if (v > m) { s = s * __expf(m - v) + 1.f; m = v; }
        else s += __expf(v - m);
    }
    #pragma unroll
    for (int off = 32; off > 0; off >>= 1) {
        float mo = __shfl_down(m, off), so = __shfl_down(s, off);
        if (mo > m) { s = s * __expf(m - mo) + so; m = mo; }
        else s += so * __expf(mo - m);
    }
    if (lane == 0) { sm[w] = m; ss[w] = s; }
    __syncthreads();
    if (t == 0) {
        for (int i = 1; i < 4; ++i) {
            float mo = sm[i], so = ss[i];
            if (mo > m) { s = s * __expf(m - mo) + so; m = mo; }
            else s += so * __expf(mo - m);
        }
        red[2 + 2 * b] = m; red[3 + 2 * b] = s;
    }
}

__global__ __launch_bounds__(64) void softmax_merge_kernel(float* __restrict__ red, int B) {
    int t = threadIdx.x;
    float m = -1e30f, s = 0.f;
    if (t < B) { m = red[2 + 2 * t]; s = red[3 + 2 * t]; }
    #pragma unroll
    for (int off = 32; off > 0; off >>= 1) {
        float mo = __shfl_down(m, off), so = __shfl_down(s, off);
        if (mo > m) { s = s * __expf(m - mo) + so; m = mo; }
        else s += so * __expf(mo - m);
    }
    if (t == 0) { red[0] = m; red[1] = s; }
}

__global__ __launch_bounds__(256) void softmax_final_kernel(
    const float* __restrict__ z, const float* __restrict__ red,
    float* __restrict__ out, int N) {
    int i = blockIdx.x * blockDim.x + threadIdx.x;
    if (i < N) out[i] = expf(z[i] - red[0]) / red[1];
}

// ---------------------------------------------------------------------------
// Host launcher
// ---------------------------------------------------------------------------
static inline char* align_up(char* p, size_t a) {
    return (char*)(((uintptr_t)p + a - 1) & ~(uintptr_t)(a - 1));
}

extern "C" void kernel_launch(void* const* d_in, const int* in_sizes, int n_in,
                              void* d_out, int out_size, void* d_ws, size_t ws_size,
                              hipStream_t stream) {
    const int N0 = N0_C, N1 = N1_C, E0 = E0_C, E1 = E1_C;
    const float* X   = (const float*)d_in[0];
    const float* W0s = (const float*)d_in[1];
    const float* W0n = (const float*)d_in[2];
    const float* b0  = (const float*)d_in[3];
    const float* W1s = (const float*)d_in[4];
    const float* W1n = (const float*)d_in[5];
    const float* b1  = (const float*)d_in[6];
    const float* W2s = (const float*)d_in[7];
    const float* W2n = (const float*)d_in[8];
    const float* b2  = (const float*)d_in[9];
    const float* Wm  = (const float*)d_in[10];
    const float* bm  = (const float*)d_in[11];
    const int* src0  = (const int*)d_in[12];
    const int* dst0  = (const int*)d_in[13];
    const int* src1  = (const int*)d_in[14];
    const int* dst1  = (const int*)d_in[15];
    const int* dsrc  = (const int*)d_in[16];
    const int* ddst  = (const int*)d_in[17];
    float* out = (float*)d_out;

    char* p = (char*)d_ws;
    const size_t FB = (size_t)N0 * D_DIM;
    const size_t SB = (size_t)N1 * D_DIM;
    auto grab_f = [&](size_t nf) { p = align_up(p, 256); float* r = (float*)p; p += nf * 4; return r; };
    auto grab_i = [&](size_t ni) { p = align_up(p, 256); int* r = (int*)p; p += ni * 4; return r; };
    auto grab_u = [&](size_t nu) { p = align_up(p, 256); ushort* r = (ushort*)p; p += nu * 2; return r; };

    float* bufA = grab_f(FB);   // y0s -> x0
    float* bufD = grab_f(FB);   // y2s
    float* x1b  = grab_f(SB);
    float* y1s  = grab_f(SB);   // -> x1f
    float* y1n  = grab_f(SB);
    float* C2   = grab_f(SB);
    float* D2   = grab_f(SB);
    float* zbuf = grab_f(N0);
    float* red  = grab_f(256);
    ushort* y0nb = grab_u(FB);  // bf16 neighbor-message planes
    ushort* y2nb = grab_u(FB);
    ushort* wt_hi = grab_u(8 * 16384);
    ushort* wt_lo = grab_u(8 * 16384);
    const int NC = N0 + 2 * N1;
    int* cntAll = grab_i(NC);
    int* rowptrAll = grab_i(NC + 1);
    int* bsum = grab_i(256);
    int* boff = grab_i(256);
    int* cursors = grab_i(128);
    int* col0 = grab_i(E0);
    int* col1 = grab_i(E1);
    int* colD = grab_i(N0);
    int2* pairbuf = (int2*)grab_i(2 * (size_t)E0);
    (void)ws_size; (void)n_in; (void)in_sizes; (void)out_size;

    const int BT = 256;
    auto cdiv = [](int a, int b) { return (a + b - 1) / b; };
    auto WT_HI = [&](int mi) { return wt_hi + ((size_t)mi << 14); };
    auto WT_LO = [&](int mi) { return wt_lo + ((size_t)mi << 14); };
    const int nbins0 = (N0 + (1 << BIN_SHIFT) - 1) >> BIN_SHIFT;   // 98

    // ---- CSR build ----
    hipMemsetAsync(cntAll, 0, (size_t)NC * 4, stream);
    hist_kernel<<<cdiv(E0, BT), BT, 0, stream>>>(dst0, cntAll, E0);
    hist_kernel<<<cdiv(E1, BT), BT, 0, stream>>>(dst1, cntAll + N0, E1);
    hist_kernel<<<cdiv(N0, BT), BT, 0, stream>>>(ddst, cntAll + N0 + N1, N0);
    const int NB = cdiv(NC, 1024);
    scan_partial_kernel<<<NB, BT, 0, stream>>>(cntAll, bsum, NC);
    exscan_kernel<<<1, 1024, 0, stream>>>(bsum, boff, NB);
    scan_final_kernel<<<NB, BT, 0, stream>>>(cntAll, boff, rowptrAll, NC);
    // graph0: binned two-pass fill (coalesced)
    initcur_kernel<<<2, 64, 0, stream>>>(rowptrAll, cursors, nbins0, N0);
    binscatter_kernel<<<cdiv(E0, 4096), BT, 0, stream>>>(src0, dst0, cursors, pairbuf, E0, nbins0);
    binfill_kernel<<<nbins0, BT, 0, stream>>>(pairbuf, rowptrAll, col0, N0);
    // small graphs: direct fill
    hipMemsetAsync(cntAll + N0, 0, (size_t)(2 * N1) * 4, stream);
    fill_kernel<<<cdiv(E1, BT), BT, 0, stream>>>(src1, dst1, rowptrAll + N0, E0, cntAll + N0, col1, E1);
    fill_kernel<<<cdiv(N0, BT), BT, 0, stream>>>(dsrc, ddst, rowptrAll + N0 + N1, E0 + E1,
                                                 cntAll + N0 + N1, colD, N0);

    // ---- weight prep ----
    wprep_kernel<<<512, BT, 0, stream>>>(W0s, W0n, W1s, W1n, W2s, W2n, wt_hi, wt_lo);

    // ---- layer 0 SAGE: x0 = X@W0s + b0 + mean_nbr(X@W0n) ----
    dualmm_mfma_kernel<<<cdiv(N0, 64), BT, 0, stream>>>(X,
        WT_HI(0), WT_LO(0), WT_HI(1), WT_LO(1), b0, nullptr, nullptr, nullptr,
        bufA, nullptr, y0nb, N0);
    csr_aggb_kernel<<<cdiv(N0, 4), BT, 0, stream>>>(y0nb, rowptrAll, 0, col0, bufA,
        nullptr, bufA, nullptr, nullptr, nullptr, N0, 0);

    // ---- down pool: x1 = relu(mean_cluster(x0)) ----
    csr_agg2_kernel<<<cdiv(N1, 4), BT, 0, stream>>>(bufA, rowptrAll + N0 + N1, E0 + E1,
        colD, nullptr, nullptr, x1b, N1, 1);

    // ---- layer 1 SAGE ----
    dualmm_mfma_kernel<<<cdiv(N1, 64), BT, 0, stream>>>(x1b,
        WT_HI(2), WT_LO(2), WT_HI(3), WT_LO(3), b1, nullptr, nullptr, nullptr,
        y1s, y1n, nullptr, N1);
    csr_agg2_kernel<<<cdiv(N1, 4), BT, 0, stream>>>(y1n, rowptrAll + N0, E0, col1, y1s,
        nullptr, y1s, N1, 1);

    // ---- layer 2: small dualmm (C2/D2 fp32), big dualmm w/ fused up-scatter ----
    dualmm_mfma_kernel<<<cdiv(N1, 64), BT, 0, stream>>>(y1s,
        WT_HI(4), WT_LO(4), WT_HI(6), WT_LO(6), nullptr, nullptr, nullptr, nullptr,
        C2, D2, nullptr, N1);
    dualmm_mfma_kernel<<<cdiv(N0, 64), BT, 0, stream>>>(bufA,
        WT_HI(5), WT_LO(5), WT_HI(7), WT_LO(7), nullptr, ddst, C2, D2,
        bufD, nullptr, y2nb, N0);

    // ---- layer 2 combine + fused readout ----
    csr_aggb_kernel<<<cdiv(N0, 4), BT, 0, stream>>>(y2nb, rowptrAll, 0, col0, bufD,
        b2, nullptr, Wm, bm, zbuf, N0, 1);

    // ---- softmax over nodes ----
    softmax_partial_kernel<<<64, BT, 0, stream>>>(zbuf, red, N0, 64);
    softmax_merge_kernel<<<1, 64, 0, stream>>>(red, 64);
    softmax_final_kernel<<<cdiv(N0, BT), BT, 0, stream>>>(zbuf, red, out, N0);
}